// Round 13
// baseline (210.004 us; speedup 1.0000x reference)
//
#include <hip/hip_runtime.h>
#include <math.h>

#define B_ROWS     32768
#define STATE_DIM  64
#define ACTION_DIM 16
#define HIDDEN     512
#define ENSEMBLE   7
#define TOP_K      5
#define IN_DIM     80    // STATE_DIM + ACTION_DIM
#define OUT_DIM    130   // 2*(STATE_DIM+1)
#define D_OUT      65    // STATE_DIM+1

// ---- MFMA kernel geometry ----
#define BM         112                           // 7 row-tiles of 16
#define MTHREADS   512                           // 8 waves; wave = 112 rows x 64 cols
#define NTILES     (B_ROWS / BM + TOP_K)         // 297 — exact-grid upper bound

// ---- packed weight dims ----
#define L1_K8 12      // K=96 (real 80)
#define L2_K8 64      // K=512
#define L3_K8 64      // K=512
#define L3_N  144     // N=130 padded to 9 col-tiles

#define N_W1 (TOP_K * L1_K8 * HIDDEN * 8)
#define N_W2 (TOP_K * L2_K8 * HIDDEN * 8)
#define N_W3 (TOP_K * L3_K8 * L3_N * 8)

#define OFF_CNT    0
#define OFF_BUCKET 256
#define OFF_W1     (OFF_BUCKET + ENSEMBLE * B_ROWS * 4)
#define OFF_W2     (OFF_W1 + N_W1 * 2)
#define OFF_W3     (OFF_W2 + N_W2 * 2)
#define WS_NEEDED  ((size_t)(OFF_W3 + N_W3 * 2))

// prep kernel: first blocks bucket, rest pack
#define BUCKET_BLOCKS ((B_ROWS + 255) / 256)
#define PACK_G        (TOP_K * (L1_K8*HIDDEN + L2_K8*HIDDEN + L3_K8*L3_N))
#define PACK_BLOCKS   ((PACK_G + 255) / 256)

typedef __attribute__((ext_vector_type(8))) _Float16 half8;
typedef __attribute__((ext_vector_type(4))) float f32x4;

// ---------------- async global->LDS stage (16B per lane, linear) ----------------
__device__ __forceinline__ void stage_tile(const char* g, char* l, int t, int bytes) {
    for (int off = t * 16; off < bytes; off += MTHREADS * 16) {
        __builtin_amdgcn_global_load_lds(
            (const __attribute__((address_space(1))) void*)(g + off),
            (__attribute__((address_space(3))) void*)(l + off), 16, 0, 0);
    }
}

// ---------------- prep: bucket rows + pack weights (fused, one launch) ----------------
// w1/w2 layout: 16KB tiles [(e*KT + k32)*2 + colhalf][4 kg][256 c][8 k] (stage-unit-major)
// w3 layout:    [e][k8][144][8] (9216B per k32-step, contiguous)
__global__ void prep_kernel(const int* __restrict__ idx,
                            int* __restrict__ cnt,
                            int* __restrict__ bucket,
                            const float* __restrict__ W1, const float* __restrict__ W2,
                            const float* __restrict__ W3,
                            _Float16* __restrict__ w1, _Float16* __restrict__ w2,
                            _Float16* __restrict__ w3) {
    if (blockIdx.x < BUCKET_BLOCKS) {
        int b = blockIdx.x * 256 + threadIdx.x;
        int lane = threadIdx.x & 63;
        int e = -1;
        if (b < B_ROWS) e = min(max(idx[b], 0), TOP_K - 1);
        #pragma unroll
        for (int ev = 0; ev < TOP_K; ++ev) {
            unsigned long long m = __ballot(e == ev);
            if (m == 0ull) continue;
            int leader = __ffsll((unsigned long long)m) - 1;
            int base = 0;
            if (lane == leader) base = atomicAdd(&cnt[ev], __popcll(m));
            base = __shfl(base, leader);
            if (e == ev) {
                int rank = __popcll(m & ((1ull << lane) - 1ull));
                bucket[ev * B_ROWS + base + rank] = b;
            }
        }
        return;
    }
    const int G1 = L1_K8 * HIDDEN;
    const int G2 = L2_K8 * HIDDEN;
    const int G3 = L3_K8 * L3_N;
    const int GPE = G1 + G2 + G3;
    int g = (blockIdx.x - BUCKET_BLOCKS) * 256 + threadIdx.x;
    if (g >= TOP_K * GPE) return;
    int e = g / GPE, r = g % GPE;

    const float* src; _Float16* dd;
    size_t dst; int k8, n, Kreal, Nreal, srcN;
    if (r < G1) {
        k8 = r / HIDDEN; n = r % HIDDEN;
        src = W1 + (size_t)e * IN_DIM * HIDDEN; Kreal = IN_DIM; Nreal = HIDDEN; srcN = HIDDEN;
        dd = w1;
        int kt = k8 >> 2, kgp = k8 & 3, hf = n >> 8, c = n & 255;
        dst = ((size_t)(((e * 3 + kt) * 2 + hf) * 4 + kgp)) * 2048 + (size_t)c * 8;
    } else if (r < G1 + G2) {
        int rr = r - G1; k8 = rr / HIDDEN; n = rr % HIDDEN;
        src = W2 + (size_t)e * HIDDEN * HIDDEN; Kreal = HIDDEN; Nreal = HIDDEN; srcN = HIDDEN;
        dd = w2;
        int kt = k8 >> 2, kgp = k8 & 3, hf = n >> 8, c = n & 255;
        dst = ((size_t)(((e * 16 + kt) * 2 + hf) * 4 + kgp)) * 2048 + (size_t)c * 8;
    } else {
        int rr = r - G1 - G2; k8 = rr / L3_N; n = rr % L3_N;
        src = W3 + (size_t)e * HIDDEN * OUT_DIM; Kreal = HIDDEN; Nreal = OUT_DIM; srcN = OUT_DIM;
        dd = w3; dst = (((size_t)e * L3_K8 + k8) * L3_N + n) * 8;
    }
    half8 hv;
    #pragma unroll
    for (int j = 0; j < 8; ++j) {
        int k = k8 * 8 + j;
        float v = (k < Kreal && n < Nreal) ? src[(size_t)k * srcN + n] : 0.f;
        hv[j] = (_Float16)v;
    }
    *(half8*)(dd + dst) = hv;
}

// ---------------- staged GEMM: per 16KB unit = (k32-step, col-half) ----------------
// A in LDS (fp16, stride ASTR, optional XOR swz); B double-buffered via global_load_lds.
// acc[7][4]: g = half*2+sub; col(g) = (g>>1)*256 + wv*32 + (g&1)*16 + lc.
template<int ASTR, bool SWZ, int NU>
__device__ __forceinline__ void gemm_staged(
    const char* A, const char* Bsrc, const float* __restrict__ bias,
    char* b0, char* b1, f32x4 (&acc)[7][4], int t, int lane, int wv)
{
    const int lc = lane & 15, kg = lane >> 4;
    #pragma unroll
    for (int g = 0; g < 4; ++g) {
        float b = bias[(g >> 1) * 256 + wv * 32 + (g & 1) * 16 + lc];
        #pragma unroll
        for (int rt = 0; rt < 7; ++rt) acc[rt][g] = (f32x4){b, b, b, b};
    }
    half8 ah[7];
    #pragma unroll
    for (int u = 0; u < NU; ++u) {
        if (u + 1 < NU)
            stage_tile(Bsrc + (size_t)(u + 1) * 16384, ((u + 1) & 1) ? b1 : b0, t, 16384);
        const char* bb = (u & 1) ? b1 : b0;
        const int ks = u >> 1;
        if ((u & 1) == 0) {
            #pragma unroll
            for (int rt = 0; rt < 7; ++rt) {
                int row = rt * 16 + lc;
                int lin = row * ASTR + ks * 64 + kg * 16;
                if (SWZ) lin ^= (row & 7) << 4;
                ah[rt] = *(const half8*)(A + lin);
            }
        }
        half8 bc0 = *(const half8*)(bb + (kg * 256 + wv * 32 + lc) * 16);
        half8 bc1 = *(const half8*)(bb + (kg * 256 + wv * 32 + 16 + lc) * 16);
        const int g0 = (u & 1) * 2;
        #pragma unroll
        for (int rt = 0; rt < 7; ++rt) {
            acc[rt][g0 + 0] = __builtin_amdgcn_mfma_f32_16x16x32_f16(ah[rt], bc0, acc[rt][g0 + 0], 0, 0, 0);
            acc[rt][g0 + 1] = __builtin_amdgcn_mfma_f32_16x16x32_f16(ah[rt], bc1, acc[rt][g0 + 1], 0, 0, 0);
        }
        __syncthreads();
    }
}

// relu + fp16 + swizzled store into h region ([112][512] fp16, stride 1024B)
__device__ __forceinline__ void store_h(char* O, f32x4 (&acc)[7][4], int lane, int wv) {
    const int lc = lane & 15, kg = lane >> 4;
    #pragma unroll
    for (int rt = 0; rt < 7; ++rt)
    #pragma unroll
    for (int g = 0; g < 4; ++g) {
        int col = (g >> 1) * 256 + wv * 32 + (g & 1) * 16 + lc;
        #pragma unroll
        for (int q = 0; q < 4; ++q) {
            int row = rt * 16 + kg * 4 + q;
            int lin = (row * 1024 + col * 2) ^ ((row & 7) << 4);
            *(_Float16*)(O + lin) = (_Float16)fmaxf(acc[rt][g][q], 0.f);
        }
    }
}

// bijective XCD-chunk swizzle for NTILES workgroups on 8 XCDs (m204 variant)
__device__ __forceinline__ int xcd_swz(int orig) {
    const int nx = 8, q = NTILES / nx, r = NTILES % nx;
    int xcd = orig % nx, pos = orig / nx;
    int base = (xcd < r) ? xcd * (q + 1) : r * (q + 1) + (xcd - r) * q;
    return base + pos;
}

// ---------------- fused MLP, fp16 MFMA, BM=112, staged B pipeline ----------------
__launch_bounds__(MTHREADS, 1)
__global__ void mlp_mfma_kernel(const float* __restrict__ state,
                                const float* __restrict__ action,
                                const float* __restrict__ eps,
                                const float* __restrict__ b1,
                                const float* __restrict__ b2,
                                const float* __restrict__ b3,
                                const _Float16* __restrict__ w1,
                                const _Float16* __restrict__ w2,
                                const _Float16* __restrict__ w3,
                                const int* __restrict__ cnt, const int* __restrict__ bucket,
                                float* __restrict__ out) {
    __shared__ char smem[147456];
    char* hs = smem;                       // [112][512] fp16 swizzled (114688 B)
    char* xs = smem;                       // [112][112] fp16 stride 224 (aliases hs, L1 only)
    float* os = (float*)smem;              // [112][132] fp32 (59136 B), overlays hs after L3
    char* bb0 = smem + 114688;             // 16KB stage buffer 0
    char* bb1 = smem + 131072;             // 16KB stage buffer 1

    // ---- exact-grid tile lookup: block j -> (e, tile), latched prefix scan ----
    const int j = xcd_swz(blockIdx.x);
    int e = TOP_K, base = 0;
    {
        int acct = 0;
        #pragma unroll
        for (int ev = 0; ev < TOP_K; ++ev) {
            int tiles = (cnt[ev] + BM - 1) / BM;
            if (e == TOP_K && j < acct + tiles) { e = ev; base = acct; }
            acct += tiles;
        }
    }
    if (e >= TOP_K) return;
    const int n    = cnt[e];
    const int tile = j - base;
    const int m0   = tile * BM;
    if (m0 >= n) return;
    const int nrows = min(BM, n - m0);
    const int t = threadIdx.x;
    const int lane = t & 63;
    const int wv = t >> 6;
    const int lc = lane & 15, kg = lane >> 4;
    const int* brow = bucket + (size_t)e * B_ROWS;

    const char* w1b = (const char*)w1 + (size_t)e * 6  * 16384;
    const char* w2b = (const char*)w2 + (size_t)e * 32 * 16384;
    const char* w3b = (const char*)w3 + (size_t)e * 16 * 9216;

    // ---- issue L1 tile0 stage early, then stage x (fp16, stride 224) ----
    stage_tile(w1b, bb0, t, 16384);
    for (int i = t; i < BM * 112; i += MTHREADS) {
        int r = i / 112, c = i % 112;
        int rb = brow[min(m0 + r, n - 1)];
        float v = 0.f;
        if (c < STATE_DIM)      v = state[(size_t)rb * STATE_DIM + c];
        else if (c < IN_DIM)    v = action[(size_t)rb * ACTION_DIM + (c - STATE_DIM)];
        *(_Float16*)(xs + r * 224 + c * 2) = (_Float16)v;
    }
    __syncthreads();                       // x visible + tile0 staged (vmcnt drained)

    f32x4 acc[7][4];

    // ---- layer 1: h1 = relu(x @ W1 + b1), K=96 (6 units) ----
    gemm_staged<224, false, 6>(xs, w1b, b1 + (size_t)e * HIDDEN, bb0, bb1, acc, t, lane, wv);
    store_h(hs, acc, lane, wv);            // overwrites xs region — all reads drained
    stage_tile(w2b, bb0, t, 16384);        // L2 tile0 (bb0 free: last L1 unit read bb1)
    __syncthreads();

    // ---- layer 2: h2 = relu(h1 @ W2 + b2), K=512 (32 units) ----
    gemm_staged<1024, true, 32>(hs, w2b, b2 + (size_t)e * HIDDEN, bb0, bb1, acc, t, lane, wv);
    store_h(hs, acc, lane, wv);            // h2 over h1 — all reads drained
    stage_tile(w3b, bb0, t, 9216);         // L3 tile0
    __syncthreads();

    // ---- layer 3: o = h2 @ W3 + b3, K=512, staged 9216B tiles, 63 units / 8 waves ----
    {
        const float* b3e = b3 + (size_t)e * OUT_DIM;
        f32x4 o[8];
        #pragma unroll
        for (int jj = 0; jj < 8; ++jj) o[jj] = (f32x4){0.f, 0.f, 0.f, 0.f};
        #pragma unroll
        for (int u = 0; u < 16; ++u) {
            if (u + 1 < 16)
                stage_tile(w3b + (size_t)(u + 1) * 9216, ((u + 1) & 1) ? bb1 : bb0, t, 9216);
            const char* bb = (u & 1) ? bb1 : bb0;
            #pragma unroll
            for (int jj = 0; jj < 8; ++jj) {
                int U = wv * 8 + jj;
                if (U < 63) {
                    int rt = U / 9, ct = U % 9;
                    int row = rt * 16 + lc;
                    int lin = (row * 1024 + u * 64 + kg * 16) ^ ((row & 7) << 4);
                    half8 ah = *(const half8*)(hs + lin);
                    half8 bh = *(const half8*)(bb + (kg * 144 + ct * 16 + lc) * 16);
                    o[jj] = __builtin_amdgcn_mfma_f32_16x16x32_f16(ah, bh, o[jj], 0, 0, 0);
                }
            }
            __syncthreads();
        }
        // write os (+bias) — overlays hs, all hs reads drained at final sync
        #pragma unroll
        for (int jj = 0; jj < 8; ++jj) {
            int U = wv * 8 + jj;
            if (U < 63) {
                int rt = U / 9, ct = U % 9;
                int col = ct * 16 + lc;
                if (col < OUT_DIM) {
                    #pragma unroll
                    for (int q = 0; q < 4; ++q)
                        os[(rt * 16 + kg * 4 + q) * 132 + col] = o[jj][q] + b3e[col];
                }
            }
        }
    }
    __syncthreads();

    // ---- epilogue ----
    for (int i = t; i < BM * D_OUT; i += MTHREADS) {
        int r = i / D_OUT, c = i % D_OUT;
        if (r >= nrows) continue;
        int rb = brow[m0 + r];
        float mu = os[r * 132 + c];
        float ls = fminf(fmaxf(os[r * 132 + c + D_OUT], -20.f), 2.f);
        float y  = fmaf(expf(ls), eps[(size_t)rb * D_OUT + c], mu);
        if (c < STATE_DIM) {
            out[(size_t)rb * STATE_DIM + c] = state[(size_t)rb * STATE_DIM + c] + y;
        } else {
            out[(size_t)B_ROWS * STATE_DIM + rb] = y;
        }
    }
}

// ================= fallback fp32 path (used if ws too small) =================
#define FB_BM      16
#define FB_THREADS 256
#define FB_TILES   ((B_ROWS + FB_BM - 1) / FB_BM)

__launch_bounds__(FB_THREADS, 2)
__global__ void mlp_fp32_kernel(const float* __restrict__ state,
                                const float* __restrict__ action,
                                const float* __restrict__ eps,
                                const float* __restrict__ W1, const float* __restrict__ b1,
                                const float* __restrict__ W2, const float* __restrict__ b2,
                                const float* __restrict__ W3, const float* __restrict__ b3,
                                const int* __restrict__ cnt, const int* __restrict__ bucket,
                                float* __restrict__ out) {
    __shared__ float xs[FB_BM][IN_DIM];
    __shared__ float h1[FB_BM][HIDDEN];
    __shared__ float h2[FB_BM][HIDDEN];
    __shared__ float os[FB_BM][OUT_DIM];
    __shared__ int   rows[FB_BM];

    const int e    = blockIdx.x / FB_TILES;
    const int tile = blockIdx.x % FB_TILES;
    const int n    = cnt[e];
    const int m0   = tile * FB_BM;
    if (m0 >= n) return;
    const int nrows = min(FB_BM, n - m0);
    const int t = threadIdx.x;

    if (t < FB_BM) rows[t] = (t < nrows) ? bucket[e * B_ROWS + m0 + t] : bucket[e * B_ROWS + m0];
    __syncthreads();

    for (int i = t; i < FB_BM * IN_DIM; i += FB_THREADS) {
        int r = i / IN_DIM, c = i % IN_DIM;
        int rb = rows[r];
        xs[r][c] = (c < STATE_DIM) ? state[(size_t)rb * STATE_DIM + c]
                                   : action[(size_t)rb * ACTION_DIM + (c - STATE_DIM)];
    }
    __syncthreads();

    const int c0 = 2 * t;
    {
        const float* We = W1 + (size_t)e * IN_DIM * HIDDEN;
        float acc0[FB_BM], acc1[FB_BM];
        const float bias0 = b1[(size_t)e * HIDDEN + c0];
        const float bias1 = b1[(size_t)e * HIDDEN + c0 + 1];
        #pragma unroll
        for (int r = 0; r < FB_BM; ++r) { acc0[r] = bias0; acc1[r] = bias1; }
        for (int k = 0; k < IN_DIM; k += 4) {
            float2 w0 = *(const float2*)&We[(size_t)(k + 0) * HIDDEN + c0];
            float2 w1v = *(const float2*)&We[(size_t)(k + 1) * HIDDEN + c0];
            float2 w2v = *(const float2*)&We[(size_t)(k + 2) * HIDDEN + c0];
            float2 w3v = *(const float2*)&We[(size_t)(k + 3) * HIDDEN + c0];
            #pragma unroll
            for (int r = 0; r < FB_BM; ++r) {
                float4 x = *(const float4*)&xs[r][k];
                acc0[r] = fmaf(x.x, w0.x, acc0[r]); acc1[r] = fmaf(x.x, w0.y, acc1[r]);
                acc0[r] = fmaf(x.y, w1v.x, acc0[r]); acc1[r] = fmaf(x.y, w1v.y, acc1[r]);
                acc0[r] = fmaf(x.z, w2v.x, acc0[r]); acc1[r] = fmaf(x.z, w2v.y, acc1[r]);
                acc0[r] = fmaf(x.w, w3v.x, acc0[r]); acc1[r] = fmaf(x.w, w3v.y, acc1[r]);
            }
        }
        #pragma unroll
        for (int r = 0; r < FB_BM; ++r)
            *(float2*)&h1[r][c0] = make_float2(fmaxf(acc0[r], 0.f), fmaxf(acc1[r], 0.f));
    }
    __syncthreads();
    {
        const float* We = W2 + (size_t)e * HIDDEN * HIDDEN;
        float acc0[FB_BM], acc1[FB_BM];
        const float bias0 = b2[(size_t)e * HIDDEN + c0];
        const float bias1 = b2[(size_t)e * HIDDEN + c0 + 1];
        #pragma unroll
        for (int r = 0; r < FB_BM; ++r) { acc0[r] = bias0; acc1[r] = bias1; }
        for (int k = 0; k < HIDDEN; k += 4) {
            float2 w0 = *(const float2*)&We[(size_t)(k + 0) * HIDDEN + c0];
            float2 w1v = *(const float2*)&We[(size_t)(k + 1) * HIDDEN + c0];
            float2 w2v = *(const float2*)&We[(size_t)(k + 2) * HIDDEN + c0];
            float2 w3v = *(const float2*)&We[(size_t)(k + 3) * HIDDEN + c0];
            #pragma unroll
            for (int r = 0; r < FB_BM; ++r) {
                float4 x = *(const float4*)&h1[r][k];
                acc0[r] = fmaf(x.x, w0.x, acc0[r]); acc1[r] = fmaf(x.x, w0.y, acc1[r]);
                acc0[r] = fmaf(x.y, w1v.x, acc0[r]); acc1[r] = fmaf(x.y, w1v.y, acc1[r]);
                acc0[r] = fmaf(x.z, w2v.x, acc0[r]); acc1[r] = fmaf(x.z, w2v.y, acc1[r]);
                acc0[r] = fmaf(x.w, w3v.x, acc0[r]); acc1[r] = fmaf(x.w, w3v.y, acc1[r]);
            }
        }
        #pragma unroll
        for (int r = 0; r < FB_BM; ++r)
            *(float2*)&h2[r][c0] = make_float2(fmaxf(acc0[r], 0.f), fmaxf(acc1[r], 0.f));
    }
    __syncthreads();
    {
        const float* We = W3 + (size_t)e * HIDDEN * OUT_DIM;
        for (int i = t; i < FB_BM * OUT_DIM; i += FB_THREADS) {
            int r = i / OUT_DIM, c = i % OUT_DIM;
            float acc = b3[(size_t)e * OUT_DIM + c];
            for (int k = 0; k < HIDDEN; k += 4) {
                float4 h = *(const float4*)&h2[r][k];
                acc = fmaf(h.x, We[(size_t)(k + 0) * OUT_DIM + c], acc);
                acc = fmaf(h.y, We[(size_t)(k + 1) * OUT_DIM + c], acc);
                acc = fmaf(h.z, We[(size_t)(k + 2) * OUT_DIM + c], acc);
                acc = fmaf(h.w, We[(size_t)(k + 3) * OUT_DIM + c], acc);
            }
            os[r][c] = acc;
        }
    }
    __syncthreads();
    for (int i = t; i < FB_BM * D_OUT; i += FB_THREADS) {
        int r = i / D_OUT, c = i % D_OUT;
        if (r >= nrows) continue;
        int rb = rows[r];
        float mu = os[r][c];
        float ls = fminf(fmaxf(os[r][c + D_OUT], -20.f), 2.f);
        float y  = fmaf(expf(ls), eps[(size_t)rb * D_OUT + c], mu);
        if (c < STATE_DIM) out[(size_t)rb * STATE_DIM + c] = state[(size_t)rb * STATE_DIM + c] + y;
        else               out[(size_t)B_ROWS * STATE_DIM + rb] = y;
    }
}

extern "C" void kernel_launch(void* const* d_in, const int* in_sizes, int n_in,
                              void* d_out, int out_size, void* d_ws, size_t ws_size,
                              hipStream_t stream) {
    const float* state  = (const float*)d_in[0];
    const float* action = (const float*)d_in[1];
    const float* eps    = (const float*)d_in[2];
    const float* W1     = (const float*)d_in[3];
    const float* b1     = (const float*)d_in[4];
    const float* W2     = (const float*)d_in[5];
    const float* b2     = (const float*)d_in[6];
    const float* W3     = (const float*)d_in[7];
    const float* b3     = (const float*)d_in[8];
    const int*   idx    = (const int*)d_in[9];
    float* out = (float*)d_out;

    int* cnt    = (int*)((char*)d_ws + OFF_CNT);
    int* bucket = (int*)((char*)d_ws + OFF_BUCKET);

    hipMemsetAsync(cnt, 0, ENSEMBLE * sizeof(int), stream);

    if (ws_size >= WS_NEEDED) {
        _Float16* w1 = (_Float16*)((char*)d_ws + OFF_W1);
        _Float16* w2 = (_Float16*)((char*)d_ws + OFF_W2);
        _Float16* w3 = (_Float16*)((char*)d_ws + OFF_W3);

        prep_kernel<<<BUCKET_BLOCKS + PACK_BLOCKS, 256, 0, stream>>>(
            idx, cnt, bucket, W1, W2, W3, w1, w2, w3);

        mlp_mfma_kernel<<<NTILES, MTHREADS, 0, stream>>>(
            state, action, eps, b1, b2, b3, w1, w2, w3, cnt, bucket, out);
    } else {
        prep_kernel<<<BUCKET_BLOCKS, 256, 0, stream>>>(
            idx, cnt, bucket, W1, W2, W3, (_Float16*)0, (_Float16*)0, (_Float16*)0);
        mlp_fp32_kernel<<<TOP_K * FB_TILES, FB_THREADS, 0, stream>>>(
            state, action, eps, W1, b1, W2, b2, W3, b3, cnt, bucket, out);
    }
}

// Round 14
// 152.676 us; speedup vs baseline: 1.3755x; 1.3755x over previous
//
#include <hip/hip_runtime.h>
#include <math.h>

#define B_ROWS     32768
#define STATE_DIM  64
#define ACTION_DIM 16
#define HIDDEN     512
#define ENSEMBLE   7
#define TOP_K      5
#define IN_DIM     80    // STATE_DIM + ACTION_DIM
#define OUT_DIM    130   // 2*(STATE_DIM+1)
#define D_OUT      65    // STATE_DIM+1

// ---- MFMA kernel geometry ----
#define BM         32
#define MTHREADS   256                           // 4 waves, each 32 rows x 128 cols
#define NTILES     (B_ROWS / BM + TOP_K)         // 1029 — exact-grid upper bound

// ---- packed weight dims ----
#define L1_K8 12      // K=96 (real 80)
#define L2_K8 64      // K=512
#define L3_K8 64      // K=512
#define L3_N  144     // N=130 padded to 9 col-tiles

#define N_W1 (TOP_K * L1_K8 * HIDDEN * 8)
#define N_W2 (TOP_K * L2_K8 * HIDDEN * 8)
#define N_W3 (TOP_K * L3_K8 * L3_N * 8)

#define OFF_CNT    0
#define OFF_BUCKET 256
#define OFF_W1     (OFF_BUCKET + ENSEMBLE * B_ROWS * 4)
#define OFF_W2     (OFF_W1 + N_W1 * 2)
#define OFF_W3     (OFF_W2 + N_W2 * 2)
#define WS_NEEDED  ((size_t)(OFF_W3 + N_W3 * 2))

// prep kernel: first blocks bucket, rest pack
#define BUCKET_BLOCKS ((B_ROWS + 255) / 256)                     // 128
#define PACK_G        (TOP_K * (L1_K8*HIDDEN + L2_K8*HIDDEN + L3_K8*L3_N))
#define PACK_BLOCKS   ((PACK_G + 255) / 256)

typedef __attribute__((ext_vector_type(8))) _Float16 half8;
typedef __attribute__((ext_vector_type(4))) float f32x4;

// ---------------- prep: bucket rows + pack weights (fused, one launch) ----------------
__global__ void prep_kernel(const int* __restrict__ idx,
                            int* __restrict__ cnt,
                            int* __restrict__ bucket,
                            const float* __restrict__ W1, const float* __restrict__ W2,
                            const float* __restrict__ W3,
                            _Float16* __restrict__ w1, _Float16* __restrict__ w2,
                            _Float16* __restrict__ w3) {
    if (blockIdx.x < BUCKET_BLOCKS) {
        int b = blockIdx.x * 256 + threadIdx.x;
        int lane = threadIdx.x & 63;
        int e = -1;
        if (b < B_ROWS) e = min(max(idx[b], 0), TOP_K - 1);
        #pragma unroll
        for (int ev = 0; ev < TOP_K; ++ev) {
            unsigned long long m = __ballot(e == ev);
            if (m == 0ull) continue;
            int leader = __ffsll((unsigned long long)m) - 1;
            int base = 0;
            if (lane == leader) base = atomicAdd(&cnt[ev], __popcll(m));
            base = __shfl(base, leader);
            if (e == ev) {
                int rank = __popcll(m & ((1ull << lane) - 1ull));
                bucket[ev * B_ROWS + base + rank] = b;
            }
        }
        return;
    }
    const int G1 = L1_K8 * HIDDEN;
    const int G2 = L2_K8 * HIDDEN;
    const int G3 = L3_K8 * L3_N;
    const int GPE = G1 + G2 + G3;
    int g = (blockIdx.x - BUCKET_BLOCKS) * 256 + threadIdx.x;
    if (g >= TOP_K * GPE) return;
    int e = g / GPE, r = g % GPE;

    const float* src; _Float16* dd;
    size_t dst; int k8, n, Kreal, Nreal, srcN;
    if (r < G1) {
        k8 = r / HIDDEN; n = r % HIDDEN;
        src = W1 + (size_t)e * IN_DIM * HIDDEN; Kreal = IN_DIM; Nreal = HIDDEN; srcN = HIDDEN;
        dd = w1; dst = (((size_t)e * L1_K8 + k8) * HIDDEN + n) * 8;
    } else if (r < G1 + G2) {
        int rr = r - G1; k8 = rr / HIDDEN; n = rr % HIDDEN;
        src = W2 + (size_t)e * HIDDEN * HIDDEN; Kreal = HIDDEN; Nreal = HIDDEN; srcN = HIDDEN;
        dd = w2; dst = (((size_t)e * L2_K8 + k8) * HIDDEN + n) * 8;
    } else {
        int rr = r - G1 - G2; k8 = rr / L3_N; n = rr % L3_N;
        src = W3 + (size_t)e * HIDDEN * OUT_DIM; Kreal = HIDDEN; Nreal = OUT_DIM; srcN = OUT_DIM;
        dd = w3; dst = (((size_t)e * L3_K8 + k8) * L3_N + n) * 8;
    }
    half8 hv;
    #pragma unroll
    for (int j = 0; j < 8; ++j) {
        int k = k8 * 8 + j;
        float v = (k < Kreal && n < Nreal) ? src[(size_t)k * srcN + n] : 0.f;
        hv[j] = (_Float16)v;
    }
    *(half8*)(dd + dst) = hv;
}

// ---------------- GEMM compute: 32 rows x 128 cols per wave ----------------
// A in LDS (fp16, row stride ASTR bytes, optional XOR swizzle); B packed [k8][Bn][8] fp16.
// 16 MFMAs per 8 B-loads per k-step; no barriers inside the k-loop (waves run free).
template<int ASTR, bool SWZ, int KSTEPS>
__device__ __forceinline__ void gemm_compute(
    const char* A,
    const _Float16* __restrict__ B, int Bn, const float* __restrict__ bias,
    f32x4 (&acc)[2][8], int lane, int col0)
{
    const int lc = lane & 15, kg = lane >> 4;
    #pragma unroll
    for (int ctl = 0; ctl < 8; ++ctl) {
        float b = bias[col0 + ctl * 16 + lc];
        acc[0][ctl] = (f32x4){b, b, b, b};
        acc[1][ctl] = acc[0][ctl];
    }
    const size_t bstep = (size_t)4 * Bn * 8;   // elements per k-step (K advances 32)
    const _Float16* bp = B + ((size_t)kg * Bn + col0 + lc) * 8;

    #pragma unroll
    for (int ks = 0; ks < KSTEPS; ++ks) {
        half8 bc[8];
        #pragma unroll
        for (int ctl = 0; ctl < 8; ++ctl)
            bc[ctl] = *(const half8*)(bp + (size_t)ks * bstep + ctl * 128);
        half8 ah[2];
        #pragma unroll
        for (int rt = 0; rt < 2; ++rt) {
            int row = rt * 16 + lc;
            int lin = row * ASTR + ks * 64 + kg * 16;
            if (SWZ) lin ^= (row & 7) << 4;
            ah[rt] = *(const half8*)(A + lin);
        }
        #pragma unroll
        for (int rt = 0; rt < 2; ++rt)
        #pragma unroll
        for (int ctl = 0; ctl < 8; ++ctl)
            acc[rt][ctl] = __builtin_amdgcn_mfma_f32_16x16x32_f16(ah[rt], bc[ctl], acc[rt][ctl], 0, 0, 0);
    }
}

// relu + fp16 + swizzled store into h region ([32][512] fp16, stride 1024B)
__device__ __forceinline__ void store_h(char* O, f32x4 (&acc)[2][8], int lane, int col0) {
    const int lc = lane & 15, kg = lane >> 4;
    #pragma unroll
    for (int rt = 0; rt < 2; ++rt)
    #pragma unroll
    for (int ctl = 0; ctl < 8; ++ctl)
    #pragma unroll
    for (int q = 0; q < 4; ++q) {
        int row = rt * 16 + kg * 4 + q;          // C layout: row=(lane>>4)*4+q
        int col = col0 + ctl * 16 + lc;          // C layout: col=lane&15
        float v = fmaxf(acc[rt][ctl][q], 0.f);
        int lin = (row * 1024 + col * 2) ^ ((row & 7) << 4);
        *(_Float16*)(O + lin) = (_Float16)v;
    }
}

// bijective XCD-chunk swizzle for NTILES workgroups on 8 XCDs (m204 variant)
__device__ __forceinline__ int xcd_swz(int orig) {
    const int nx = 8, q = NTILES / nx, r = NTILES % nx;
    int xcd = orig % nx, pos = orig / nx;
    int base = (xcd < r) ? xcd * (q + 1) : r * (q + 1) + (xcd - r) * q;
    return base + pos;
}

// ---------------- fused MLP, fp16 MFMA, BM=32, 4 waves (32x128 per wave) ----------------
__launch_bounds__(MTHREADS, 1)
__global__ void mlp_mfma_kernel(const float* __restrict__ state,
                                const float* __restrict__ action,
                                const float* __restrict__ eps,
                                const float* __restrict__ b1,
                                const float* __restrict__ b2,
                                const float* __restrict__ b3,
                                const _Float16* __restrict__ w1,
                                const _Float16* __restrict__ w2,
                                const _Float16* __restrict__ w3,
                                const int* __restrict__ cnt, const int* __restrict__ bucket,
                                float* __restrict__ out) {
    __shared__ char smem[39936];
    char* xs = smem;                     // [32][112] fp16, stride 224B (7168 B)
    char* hs = smem + 7168;              // [32][512] fp16 swizzled (32768 B) — h1 then h2
    float* os = (float*)(smem + 7168);   // [32][132] fp32 (16896 B), overlays h after layer 3

    // ---- exact-grid tile lookup: block j -> (e, tile), latched prefix scan ----
    const int j = xcd_swz(blockIdx.x);
    int e = TOP_K, base = 0;
    {
        int acct = 0;
        #pragma unroll
        for (int ev = 0; ev < TOP_K; ++ev) {
            int tiles = (cnt[ev] + BM - 1) / BM;
            if (e == TOP_K && j < acct + tiles) { e = ev; base = acct; }
            acct += tiles;
        }
    }
    if (e >= TOP_K) return;
    const int n    = cnt[e];
    const int tile = j - base;
    const int m0   = tile * BM;
    if (m0 >= n) return;
    const int nrows = min(BM, n - m0);
    const int t = threadIdx.x;
    const int lane = t & 63;
    const int wv = t >> 6;
    const int col0 = wv * 128;           // 4 col-groups x 128 cols
    const int* brow = bucket + (size_t)e * B_ROWS;

    // ---- stage x = concat(state, action) fp16, 32x112 (cols>=80 zero) ----
    for (int i = t; i < BM * 112; i += MTHREADS) {
        int r = i / 112, c = i % 112;
        int rb = brow[min(m0 + r, n - 1)];
        float v = 0.f;
        if (c < STATE_DIM)      v = state[(size_t)rb * STATE_DIM + c];
        else if (c < IN_DIM)    v = action[(size_t)rb * ACTION_DIM + (c - STATE_DIM)];
        *(_Float16*)(xs + r * 224 + c * 2) = (_Float16)v;
    }
    __syncthreads();

    f32x4 acc[2][8];

    // ---- layer 1: h1 = relu(x @ W1 + b1), K=96, N=512 ----
    gemm_compute<224, false, 3>(xs,
        w1 + (size_t)e * L1_K8 * HIDDEN * 8,
        HIDDEN, b1 + (size_t)e * HIDDEN, acc, lane, col0);
    store_h(hs, acc, lane, col0);        // h region disjoint from x: no WAR hazard
    __syncthreads();

    // ---- layer 2: h2 = relu(h1 @ W2 + b2), K=512, N=512; h2 in regs until barrier ----
    gemm_compute<1024, true, 16>(hs,
        w2 + (size_t)e * L2_K8 * HIDDEN * 8,
        HIDDEN, b2 + (size_t)e * HIDDEN, acc, lane, col0);
    __syncthreads();                     // all h1 reads complete
    store_h(hs, acc, lane, col0);        // overwrite h1 with h2
    __syncthreads();

    // ---- layer 3: o = h2 @ W3 + b3, K=512, N=144 ----
    // 18 units = 2 row-tiles x 9 col-tiles over 4 waves.
    // Wave wv: rt=wv&1, ct={ct0, ct0+2, ct0+4, ct0+6} with ct0=wv>>1 (0/1);
    // waves 0,1 also ct=8 (rt=wv).
    {
        const _Float16* Bw = w3 + (size_t)e * L3_K8 * L3_N * 8;
        const float* b3e = b3 + (size_t)e * OUT_DIM;
        const int lc = lane & 15, kg = lane >> 4;
        const int rt  = wv & 1;
        const int ct0 = wv >> 1;             // 0 or 1
        const bool fifth = (wv < 2);         // ct=8
        f32x4 o0 = {0.f,0.f,0.f,0.f}, o1 = o0, o2 = o0, o3 = o0, o4 = o0;
        const size_t bstep = (size_t)4 * L3_N * 8;
        const _Float16* bp0 = Bw + ((size_t)kg * L3_N + (ct0 + 0) * 16 + lc) * 8;
        const _Float16* bp1 = Bw + ((size_t)kg * L3_N + (ct0 + 2) * 16 + lc) * 8;
        const _Float16* bp2 = Bw + ((size_t)kg * L3_N + (ct0 + 4) * 16 + lc) * 8;
        const _Float16* bp3 = Bw + ((size_t)kg * L3_N + (ct0 + 6) * 16 + lc) * 8;
        const _Float16* bp4 = Bw + ((size_t)kg * L3_N + 8 * 16 + lc) * 8;

        #pragma unroll
        for (int ks = 0; ks < 16; ++ks) {
            int row = rt * 16 + lc;
            int lin = (row * 1024 + ks * 64 + kg * 16) ^ ((row & 7) << 4);
            half8 ah = *(const half8*)(hs + lin);
            half8 v0 = *(const half8*)(bp0 + (size_t)ks * bstep);
            half8 v1 = *(const half8*)(bp1 + (size_t)ks * bstep);
            half8 v2 = *(const half8*)(bp2 + (size_t)ks * bstep);
            half8 v3 = *(const half8*)(bp3 + (size_t)ks * bstep);
            o0 = __builtin_amdgcn_mfma_f32_16x16x32_f16(ah, v0, o0, 0, 0, 0);
            o1 = __builtin_amdgcn_mfma_f32_16x16x32_f16(ah, v1, o1, 0, 0, 0);
            o2 = __builtin_amdgcn_mfma_f32_16x16x32_f16(ah, v2, o2, 0, 0, 0);
            o3 = __builtin_amdgcn_mfma_f32_16x16x32_f16(ah, v3, o3, 0, 0, 0);
            if (fifth) {
                half8 v4 = *(const half8*)(bp4 + (size_t)ks * bstep);
                o4 = __builtin_amdgcn_mfma_f32_16x16x32_f16(ah, v4, o4, 0, 0, 0);
            }
        }
        __syncthreads();                 // all h2 reads complete (os overlays h)
        {
            // cols: (ct0+{0,2,4,6})*16+lc — max (1+6)*16+15=127 < OUT_DIM, always valid
            int c0 = (ct0 + 0) * 16 + lc;
            int c1 = (ct0 + 2) * 16 + lc;
            int c2 = (ct0 + 4) * 16 + lc;
            int c3 = (ct0 + 6) * 16 + lc;
            #pragma unroll
            for (int q = 0; q < 4; ++q) {
                int row = rt * 16 + kg * 4 + q;
                os[row * 132 + c0] = o0[q] + b3e[c0];
                os[row * 132 + c1] = o1[q] + b3e[c1];
                os[row * 132 + c2] = o2[q] + b3e[c2];
                os[row * 132 + c3] = o3[q] + b3e[c3];
            }
            if (fifth) {
                int c4 = 128 + lc;
                if (c4 < OUT_DIM) {
                    #pragma unroll
                    for (int q = 0; q < 4; ++q) {
                        int row = rt * 16 + kg * 4 + q;
                        os[row * 132 + c4] = o4[q] + b3e[c4];
                    }
                }
            }
        }
    }
    __syncthreads();

    // ---- epilogue ----
    for (int i = t; i < BM * D_OUT; i += MTHREADS) {
        int r = i / D_OUT, c = i % D_OUT;
        if (r >= nrows) continue;
        int rb = brow[m0 + r];
        float mu = os[r * 132 + c];
        float ls = fminf(fmaxf(os[r * 132 + c + D_OUT], -20.f), 2.f);
        float y  = fmaf(expf(ls), eps[(size_t)rb * D_OUT + c], mu);
        if (c < STATE_DIM) {
            out[(size_t)rb * STATE_DIM + c] = state[(size_t)rb * STATE_DIM + c] + y;
        } else {
            out[(size_t)B_ROWS * STATE_DIM + rb] = y;
        }
    }
}

// ================= fallback fp32 path (used if ws too small) =================
#define FB_BM      16
#define FB_THREADS 256
#define FB_TILES   ((B_ROWS + FB_BM - 1) / FB_BM)

__launch_bounds__(FB_THREADS, 2)
__global__ void mlp_fp32_kernel(const float* __restrict__ state,
                                const float* __restrict__ action,
                                const float* __restrict__ eps,
                                const float* __restrict__ W1, const float* __restrict__ b1,
                                const float* __restrict__ W2, const float* __restrict__ b2,
                                const float* __restrict__ W3, const float* __restrict__ b3,
                                const int* __restrict__ cnt, const int* __restrict__ bucket,
                                float* __restrict__ out) {
    __shared__ float xs[FB_BM][IN_DIM];
    __shared__ float h1[FB_BM][HIDDEN];
    __shared__ float h2[FB_BM][HIDDEN];
    __shared__ float os[FB_BM][OUT_DIM];
    __shared__ int   rows[FB_BM];

    const int e    = blockIdx.x / FB_TILES;
    const int tile = blockIdx.x % FB_TILES;
    const int n    = cnt[e];
    const int m0   = tile * FB_BM;
    if (m0 >= n) return;
    const int nrows = min(FB_BM, n - m0);
    const int t = threadIdx.x;

    if (t < FB_BM) rows[t] = (t < nrows) ? bucket[e * B_ROWS + m0 + t] : bucket[e * B_ROWS + m0];
    __syncthreads();

    for (int i = t; i < FB_BM * IN_DIM; i += FB_THREADS) {
        int r = i / IN_DIM, c = i % IN_DIM;
        int rb = rows[r];
        xs[r][c] = (c < STATE_DIM) ? state[(size_t)rb * STATE_DIM + c]
                                   : action[(size_t)rb * ACTION_DIM + (c - STATE_DIM)];
    }
    __syncthreads();

    const int c0 = 2 * t;
    {
        const float* We = W1 + (size_t)e * IN_DIM * HIDDEN;
        float acc0[FB_BM], acc1[FB_BM];
        const float bias0 = b1[(size_t)e * HIDDEN + c0];
        const float bias1 = b1[(size_t)e * HIDDEN + c0 + 1];
        #pragma unroll
        for (int r = 0; r < FB_BM; ++r) { acc0[r] = bias0; acc1[r] = bias1; }
        for (int k = 0; k < IN_DIM; k += 4) {
            float2 w0 = *(const float2*)&We[(size_t)(k + 0) * HIDDEN + c0];
            float2 w1v = *(const float2*)&We[(size_t)(k + 1) * HIDDEN + c0];
            float2 w2v = *(const float2*)&We[(size_t)(k + 2) * HIDDEN + c0];
            float2 w3v = *(const float2*)&We[(size_t)(k + 3) * HIDDEN + c0];
            #pragma unroll
            for (int r = 0; r < FB_BM; ++r) {
                float4 x = *(const float4*)&xs[r][k];
                acc0[r] = fmaf(x.x, w0.x, acc0[r]); acc1[r] = fmaf(x.x, w0.y, acc1[r]);
                acc0[r] = fmaf(x.y, w1v.x, acc0[r]); acc1[r] = fmaf(x.y, w1v.y, acc1[r]);
                acc0[r] = fmaf(x.z, w2v.x, acc0[r]); acc1[r] = fmaf(x.z, w2v.y, acc1[r]);
                acc0[r] = fmaf(x.w, w3v.x, acc0[r]); acc1[r] = fmaf(x.w, w3v.y, acc1[r]);
            }
        }
        #pragma unroll
        for (int r = 0; r < FB_BM; ++r)
            *(float2*)&h1[r][c0] = make_float2(fmaxf(acc0[r], 0.f), fmaxf(acc1[r], 0.f));
    }
    __syncthreads();
    {
        const float* We = W2 + (size_t)e * HIDDEN * HIDDEN;
        float acc0[FB_BM], acc1[FB_BM];
        const float bias0 = b2[(size_t)e * HIDDEN + c0];
        const float bias1 = b2[(size_t)e * HIDDEN + c0 + 1];
        #pragma unroll
        for (int r = 0; r < FB_BM; ++r) { acc0[r] = bias0; acc1[r] = bias1; }
        for (int k = 0; k < HIDDEN; k += 4) {
            float2 w0 = *(const float2*)&We[(size_t)(k + 0) * HIDDEN + c0];
            float2 w1v = *(const float2*)&We[(size_t)(k + 1) * HIDDEN + c0];
            float2 w2v = *(const float2*)&We[(size_t)(k + 2) * HIDDEN + c0];
            float2 w3v = *(const float2*)&We[(size_t)(k + 3) * HIDDEN + c0];
            #pragma unroll
            for (int r = 0; r < FB_BM; ++r) {
                float4 x = *(const float4*)&h1[r][k];
                acc0[r] = fmaf(x.x, w0.x, acc0[r]); acc1[r] = fmaf(x.x, w0.y, acc1[r]);
                acc0[r] = fmaf(x.y, w1v.x, acc0[r]); acc1[r] = fmaf(x.y, w1v.y, acc1[r]);
                acc0[r] = fmaf(x.z, w2v.x, acc0[r]); acc1[r] = fmaf(x.z, w2v.y, acc1[r]);
                acc0[r] = fmaf(x.w, w3v.x, acc0[r]); acc1[r] = fmaf(x.w, w3v.y, acc1[r]);
            }
        }
        #pragma unroll
        for (int r = 0; r < FB_BM; ++r)
            *(float2*)&h2[r][c0] = make_float2(fmaxf(acc0[r], 0.f), fmaxf(acc1[r], 0.f));
    }
    __syncthreads();
    {
        const float* We = W3 + (size_t)e * HIDDEN * OUT_DIM;
        for (int i = t; i < FB_BM * OUT_DIM; i += FB_THREADS) {
            int r = i / OUT_DIM, c = i % OUT_DIM;
            float acc = b3[(size_t)e * OUT_DIM + c];
            for (int k = 0; k < HIDDEN; k += 4) {
                float4 h = *(const float4*)&h2[r][k];
                acc = fmaf(h.x, We[(size_t)(k + 0) * OUT_DIM + c], acc);
                acc = fmaf(h.y, We[(size_t)(k + 1) * OUT_DIM + c], acc);
                acc = fmaf(h.z, We[(size_t)(k + 2) * OUT_DIM + c], acc);
                acc = fmaf(h.w, We[(size_t)(k + 3) * OUT_DIM + c], acc);
            }
            os[r][c] = acc;
        }
    }
    __syncthreads();
    for (int i = t; i < FB_BM * D_OUT; i += FB_THREADS) {
        int r = i / D_OUT, c = i % D_OUT;
        if (r >= nrows) continue;
        int rb = rows[r];
        float mu = os[r][c];
        float ls = fminf(fmaxf(os[r][c + D_OUT], -20.f), 2.f);
        float y  = fmaf(expf(ls), eps[(size_t)rb * D_OUT + c], mu);
        if (c < STATE_DIM) out[(size_t)rb * STATE_DIM + c] = state[(size_t)rb * STATE_DIM + c] + y;
        else               out[(size_t)B_ROWS * STATE_DIM + rb] = y;
    }
}

extern "C" void kernel_launch(void* const* d_in, const int* in_sizes, int n_in,
                              void* d_out, int out_size, void* d_ws, size_t ws_size,
                              hipStream_t stream) {
    const float* state  = (const float*)d_in[0];
    const float* action = (const float*)d_in[1];
    const float* eps    = (const float*)d_in[2];
    const float* W1     = (const float*)d_in[3];
    const float* b1     = (const float*)d_in[4];
    const float* W2     = (const float*)d_in[5];
    const float* b2     = (const float*)d_in[6];
    const float* W3     = (const float*)d_in[7];
    const float* b3     = (const float*)d_in[8];
    const int*   idx    = (const int*)d_in[9];
    float* out = (float*)d_out;

    int* cnt    = (int*)((char*)d_ws + OFF_CNT);
    int* bucket = (int*)((char*)d_ws + OFF_BUCKET);

    hipMemsetAsync(cnt, 0, ENSEMBLE * sizeof(int), stream);

    if (ws_size >= WS_NEEDED) {
        _Float16* w1 = (_Float16*)((char*)d_ws + OFF_W1);
        _Float16* w2 = (_Float16*)((char*)d_ws + OFF_W2);
        _Float16* w3 = (_Float16*)((char*)d_ws + OFF_W3);

        prep_kernel<<<BUCKET_BLOCKS + PACK_BLOCKS, 256, 0, stream>>>(
            idx, cnt, bucket, W1, W2, W3, w1, w2, w3);

        mlp_mfma_kernel<<<NTILES, MTHREADS, 0, stream>>>(
            state, action, eps, b1, b2, b3, w1, w2, w3, cnt, bucket, out);
    } else {
        prep_kernel<<<BUCKET_BLOCKS, 256, 0, stream>>>(
            idx, cnt, bucket, W1, W2, W3, (_Float16*)0, (_Float16*)0, (_Float16*)0);
        mlp_fp32_kernel<<<TOP_K * FB_TILES, FB_THREADS, 0, stream>>>(
            state, action, eps, W1, b1, W2, b2, W3, b3, cnt, bucket, out);
    }
}

// Round 15
// 146.586 us; speedup vs baseline: 1.4326x; 1.0415x over previous
//
#include <hip/hip_runtime.h>
#include <math.h>

#define B_ROWS     32768
#define STATE_DIM  64
#define ACTION_DIM 16
#define HIDDEN     512
#define ENSEMBLE   7
#define TOP_K      5
#define IN_DIM     80    // STATE_DIM + ACTION_DIM
#define OUT_DIM    130   // 2*(STATE_DIM+1)
#define D_OUT      65    // STATE_DIM+1

// ---- MFMA kernel geometry ----
#define BM         32
#define MTHREADS   512                           // 8 waves, each 32 rows x 64 cols
#define NTILES     (B_ROWS / BM + TOP_K)         // 1029 — exact-grid upper bound

// ---- packed weight dims ----
#define L1_K8 12      // K=96 (real 80)
#define L2_K8 64      // K=512
#define L3_K8 64      // K=512
#define L3_N  144     // N=130 padded to 9 col-tiles

#define N_W1 (TOP_K * L1_K8 * HIDDEN * 8)
#define N_W2 (TOP_K * L2_K8 * HIDDEN * 8)
#define N_W3 (TOP_K * L3_K8 * L3_N * 8)

#define OFF_CNT    0
#define OFF_BUCKET 256
#define OFF_W1     (OFF_BUCKET + ENSEMBLE * B_ROWS * 4)
#define OFF_W2     (OFF_W1 + N_W1 * 2)
#define OFF_W3     (OFF_W2 + N_W2 * 2)
#define WS_NEEDED  ((size_t)(OFF_W3 + N_W3 * 2))

// prep kernel: first blocks bucket, rest pack
#define BUCKET_BLOCKS ((B_ROWS + 255) / 256)
#define PACK_G        (TOP_K * (L1_K8*HIDDEN + L2_K8*HIDDEN + L3_K8*L3_N))
#define PACK_BLOCKS   ((PACK_G + 255) / 256)

typedef __attribute__((ext_vector_type(8))) _Float16 half8;
typedef __attribute__((ext_vector_type(4))) float f32x4;

// ---------------- async global->LDS stage (16B per lane, linear) ----------------
__device__ __forceinline__ void stage_tile(const char* g, char* l, int t, int bytes) {
    for (int off = t * 16; off < bytes; off += MTHREADS * 16) {
        __builtin_amdgcn_global_load_lds(
            (const __attribute__((address_space(1))) void*)(g + off),
            (__attribute__((address_space(3))) void*)(l + off), 16, 0, 0);
    }
}

// ---------------- prep: bucket rows + pack weights (fused, one launch) ----------------
// w1/w2 layout: 16KB tiles [(e*KT + k32)*2 + colhalf][4 kg][256 c][8 k] (stage-unit-major)
// w3 layout:    [e][k8][144][8]
__global__ void prep_kernel(const int* __restrict__ idx,
                            int* __restrict__ cnt,
                            int* __restrict__ bucket,
                            const float* __restrict__ W1, const float* __restrict__ W2,
                            const float* __restrict__ W3,
                            _Float16* __restrict__ w1, _Float16* __restrict__ w2,
                            _Float16* __restrict__ w3) {
    if (blockIdx.x < BUCKET_BLOCKS) {
        int b = blockIdx.x * 256 + threadIdx.x;
        int lane = threadIdx.x & 63;
        int e = -1;
        if (b < B_ROWS) e = min(max(idx[b], 0), TOP_K - 1);
        #pragma unroll
        for (int ev = 0; ev < TOP_K; ++ev) {
            unsigned long long m = __ballot(e == ev);
            if (m == 0ull) continue;
            int leader = __ffsll((unsigned long long)m) - 1;
            int base = 0;
            if (lane == leader) base = atomicAdd(&cnt[ev], __popcll(m));
            base = __shfl(base, leader);
            if (e == ev) {
                int rank = __popcll(m & ((1ull << lane) - 1ull));
                bucket[ev * B_ROWS + base + rank] = b;
            }
        }
        return;
    }
    const int G1 = L1_K8 * HIDDEN;
    const int G2 = L2_K8 * HIDDEN;
    const int G3 = L3_K8 * L3_N;
    const int GPE = G1 + G2 + G3;
    int g = (blockIdx.x - BUCKET_BLOCKS) * 256 + threadIdx.x;
    if (g >= TOP_K * GPE) return;
    int e = g / GPE, r = g % GPE;

    const float* src; _Float16* dd;
    size_t dst; int k8, n, Kreal, Nreal, srcN;
    if (r < G1) {
        k8 = r / HIDDEN; n = r % HIDDEN;
        src = W1 + (size_t)e * IN_DIM * HIDDEN; Kreal = IN_DIM; Nreal = HIDDEN; srcN = HIDDEN;
        dd = w1;
        int kt = k8 >> 2, kgp = k8 & 3, hf = n >> 8, c = n & 255;
        dst = ((size_t)(((e * 3 + kt) * 2 + hf) * 4 + kgp)) * 2048 + (size_t)c * 8;
    } else if (r < G1 + G2) {
        int rr = r - G1; k8 = rr / HIDDEN; n = rr % HIDDEN;
        src = W2 + (size_t)e * HIDDEN * HIDDEN; Kreal = HIDDEN; Nreal = HIDDEN; srcN = HIDDEN;
        dd = w2;
        int kt = k8 >> 2, kgp = k8 & 3, hf = n >> 8, c = n & 255;
        dst = ((size_t)(((e * 16 + kt) * 2 + hf) * 4 + kgp)) * 2048 + (size_t)c * 8;
    } else {
        int rr = r - G1 - G2; k8 = rr / L3_N; n = rr % L3_N;
        src = W3 + (size_t)e * HIDDEN * OUT_DIM; Kreal = HIDDEN; Nreal = OUT_DIM; srcN = OUT_DIM;
        dd = w3; dst = (((size_t)e * L3_K8 + k8) * L3_N + n) * 8;
    }
    half8 hv;
    #pragma unroll
    for (int j = 0; j < 8; ++j) {
        int k = k8 * 8 + j;
        float v = (k < Kreal && n < Nreal) ? src[(size_t)k * srcN + n] : 0.f;
        hv[j] = (_Float16)v;
    }
    *(half8*)(dd + dst) = hv;
}

// ---------------- staged GEMM: unit = 16KB (k32-step x 256-col half) ----------------
// A in LDS (fp16, stride ASTR, optional XOR swz); B double-buffered via global_load_lds.
// acc[2][4]: g = (u&1)*2 + sub; col(g) = (g>>1)*256 + wv*32 + (g&1)*16 + lc.
template<int ASTR, bool SWZ, int NU>
__device__ __forceinline__ void gemm_staged(
    const char* A, const char* Bsrc, const float* __restrict__ bias,
    char* b0, char* b1, f32x4 (&acc)[2][4], int t, int lane, int wv)
{
    const int lc = lane & 15, kg = lane >> 4;
    #pragma unroll
    for (int g = 0; g < 4; ++g) {
        float b = bias[(g >> 1) * 256 + wv * 32 + (g & 1) * 16 + lc];
        acc[0][g] = (f32x4){b, b, b, b};
        acc[1][g] = acc[0][g];
    }
    half8 ah[2];
    #pragma unroll
    for (int u = 0; u < NU; ++u) {
        if (u + 1 < NU)
            stage_tile(Bsrc + (size_t)(u + 1) * 16384, ((u + 1) & 1) ? b1 : b0, t, 16384);
        const char* bb = (u & 1) ? b1 : b0;
        const int ks = u >> 1;
        if ((u & 1) == 0) {
            #pragma unroll
            for (int rt = 0; rt < 2; ++rt) {
                int row = rt * 16 + lc;
                int lin = row * ASTR + ks * 64 + kg * 16;
                if (SWZ) lin ^= (row & 7) << 4;
                ah[rt] = *(const half8*)(A + lin);
            }
        }
        half8 bc0 = *(const half8*)(bb + (kg * 256 + wv * 32 + lc) * 16);
        half8 bc1 = *(const half8*)(bb + (kg * 256 + wv * 32 + 16 + lc) * 16);
        const int g0 = (u & 1) * 2;
        #pragma unroll
        for (int rt = 0; rt < 2; ++rt) {
            acc[rt][g0 + 0] = __builtin_amdgcn_mfma_f32_16x16x32_f16(ah[rt], bc0, acc[rt][g0 + 0], 0, 0, 0);
            acc[rt][g0 + 1] = __builtin_amdgcn_mfma_f32_16x16x32_f16(ah[rt], bc1, acc[rt][g0 + 1], 0, 0, 0);
        }
        __syncthreads();
    }
}

// relu + fp16 + swizzled store into h region ([32][512] fp16, stride 1024B)
__device__ __forceinline__ void store_h(char* O, f32x4 (&acc)[2][4], int lane, int wv) {
    const int lc = lane & 15, kg = lane >> 4;
    #pragma unroll
    for (int rt = 0; rt < 2; ++rt)
    #pragma unroll
    for (int g = 0; g < 4; ++g) {
        int col = (g >> 1) * 256 + wv * 32 + (g & 1) * 16 + lc;
        #pragma unroll
        for (int q = 0; q < 4; ++q) {
            int row = rt * 16 + kg * 4 + q;
            int lin = (row * 1024 + col * 2) ^ ((row & 7) << 4);
            *(_Float16*)(O + lin) = (_Float16)fmaxf(acc[rt][g][q], 0.f);
        }
    }
}

// bijective XCD-chunk swizzle for NTILES workgroups on 8 XCDs (m204 variant)
__device__ __forceinline__ int xcd_swz(int orig) {
    const int nx = 8, q = NTILES / nx, r = NTILES % nx;
    int xcd = orig % nx, pos = orig / nx;
    int base = (xcd < r) ? xcd * (q + 1) : r * (q + 1) + (xcd - r) * q;
    return base + pos;
}

// ---------------- fused MLP, fp16 MFMA, BM=32, 8 waves, staged B (m97-style) ----------------
__launch_bounds__(MTHREADS, 1)
__global__ void mlp_mfma_kernel(const float* __restrict__ state,
                                const float* __restrict__ action,
                                const float* __restrict__ eps,
                                const float* __restrict__ b1,
                                const float* __restrict__ b2,
                                const float* __restrict__ b3,
                                const _Float16* __restrict__ w1,
                                const _Float16* __restrict__ w2,
                                const _Float16* __restrict__ w3,
                                const int* __restrict__ cnt, const int* __restrict__ bucket,
                                float* __restrict__ out) {
    __shared__ char smem[72704];
    char* xs = smem;                     // [32][112] fp16, stride 224B (7168 B)
    char* hs = smem + 7168;              // [32][512] fp16 swizzled (32768 B) — h1 then h2
    float* os = (float*)(smem + 7168);   // [32][132] fp32 (16896 B), overlays h after L3
    char* bb0 = smem + 39936;            // 16KB stage buffer 0
    char* bb1 = smem + 56320;            // 16KB stage buffer 1

    // ---- exact-grid tile lookup: block j -> (e, tile), latched prefix scan ----
    const int j = xcd_swz(blockIdx.x);
    int e = TOP_K, base = 0;
    {
        int acct = 0;
        #pragma unroll
        for (int ev = 0; ev < TOP_K; ++ev) {
            int tiles = (cnt[ev] + BM - 1) / BM;
            if (e == TOP_K && j < acct + tiles) { e = ev; base = acct; }
            acct += tiles;
        }
    }
    if (e >= TOP_K) return;
    const int n    = cnt[e];
    const int tile = j - base;
    const int m0   = tile * BM;
    if (m0 >= n) return;
    const int nrows = min(BM, n - m0);
    const int t = threadIdx.x;
    const int lane = t & 63;
    const int wv = t >> 6;
    const int lc = lane & 15, kg = lane >> 4;
    const int* brow = bucket + (size_t)e * B_ROWS;

    const char* w1b = (const char*)w1 + (size_t)e * 6  * 16384;
    const char* w2b = (const char*)w2 + (size_t)e * 32 * 16384;

    // ---- issue L1 tile0 stage early, then stage x (fp16, stride 224) ----
    stage_tile(w1b, bb0, t, 16384);
    for (int i = t; i < BM * 112; i += MTHREADS) {
        int r = i / 112, c = i % 112;
        int rb = brow[min(m0 + r, n - 1)];
        float v = 0.f;
        if (c < STATE_DIM)      v = state[(size_t)rb * STATE_DIM + c];
        else if (c < IN_DIM)    v = action[(size_t)rb * ACTION_DIM + (c - STATE_DIM)];
        *(_Float16*)(xs + r * 224 + c * 2) = (_Float16)v;
    }
    __syncthreads();                     // x visible + tile0 staged (vmcnt drained)

    f32x4 acc[2][4];

    // ---- layer 1: h1 = relu(x @ W1 + b1), K=96 (6 units) ----
    gemm_staged<224, false, 6>(xs, w1b, b1 + (size_t)e * HIDDEN, bb0, bb1, acc, t, lane, wv);
    store_h(hs, acc, lane, wv);          // hs disjoint from xs: no WAR hazard
    stage_tile(w2b, bb0, t, 16384);      // L2 tile0 (bb0 free: last L1 unit read bb1)
    __syncthreads();

    // ---- layer 2: h2 = relu(h1 @ W2 + b2), K=512 (32 units); h2 in regs until barrier ----
    gemm_staged<1024, true, 32>(hs, w2b, b2 + (size_t)e * HIDDEN, bb0, bb1, acc, t, lane, wv);
    store_h(hs, acc, lane, wv);          // overwrite h1 with h2 (last unit's barrier drained reads)
    __syncthreads();

    // ---- layer 3: o = h2 @ W3 + b3, K=512, N=144, direct global B (r8 mapping) ----
    {
        const _Float16* Bw = w3 + (size_t)e * L3_K8 * L3_N * 8;
        const float* b3e = b3 + (size_t)e * OUT_DIM;
        const int rt  = wv & 1;
        const int ct0 = wv >> 1;             // 0..3
        const bool third = (wv < 2);         // ct=8
        f32x4 o0 = {0.f,0.f,0.f,0.f}, o1 = o0, o2 = o0;
        const size_t bstep = (size_t)4 * L3_N * 8;
        const _Float16* bp0 = Bw + ((size_t)kg * L3_N + ct0 * 16 + lc) * 8;
        const _Float16* bp1 = Bw + ((size_t)kg * L3_N + (ct0 + 4) * 16 + lc) * 8;
        const _Float16* bp2 = Bw + ((size_t)kg * L3_N + 8 * 16 + lc) * 8;

        #pragma unroll
        for (int ks = 0; ks < 16; ++ks) {
            int row = rt * 16 + lc;
            int lin = (row * 1024 + ks * 64 + kg * 16) ^ ((row & 7) << 4);
            half8 ah = *(const half8*)(hs + lin);
            half8 v0 = *(const half8*)(bp0 + (size_t)ks * bstep);
            half8 v1 = *(const half8*)(bp1 + (size_t)ks * bstep);
            o0 = __builtin_amdgcn_mfma_f32_16x16x32_f16(ah, v0, o0, 0, 0, 0);
            o1 = __builtin_amdgcn_mfma_f32_16x16x32_f16(ah, v1, o1, 0, 0, 0);
            if (third) {
                half8 v2 = *(const half8*)(bp2 + (size_t)ks * bstep);
                o2 = __builtin_amdgcn_mfma_f32_16x16x32_f16(ah, v2, o2, 0, 0, 0);
            }
        }
        __syncthreads();                 // all h2 reads complete (os overlays hs)
        {
            int c0 = ct0 * 16 + lc;
            int c1 = (ct0 + 4) * 16 + lc;
            #pragma unroll
            for (int q = 0; q < 4; ++q) {
                int row = rt * 16 + kg * 4 + q;
                os[row * 132 + c0] = o0[q] + b3e[c0];
                if (c1 < OUT_DIM) os[row * 132 + c1] = o1[q] + b3e[c1];
            }
            if (third) {
                int c2 = 128 + lc;
                if (c2 < OUT_DIM) {
                    #pragma unroll
                    for (int q = 0; q < 4; ++q) {
                        int row = rt * 16 + kg * 4 + q;
                        os[row * 132 + c2] = o2[q] + b3e[c2];
                    }
                }
            }
        }
    }
    __syncthreads();

    // ---- epilogue ----
    for (int i = t; i < BM * D_OUT; i += MTHREADS) {
        int r = i / D_OUT, c = i % D_OUT;
        if (r >= nrows) continue;
        int rb = brow[m0 + r];
        float mu = os[r * 132 + c];
        float ls = fminf(fmaxf(os[r * 132 + c + D_OUT], -20.f), 2.f);
        float y  = fmaf(expf(ls), eps[(size_t)rb * D_OUT + c], mu);
        if (c < STATE_DIM) {
            out[(size_t)rb * STATE_DIM + c] = state[(size_t)rb * STATE_DIM + c] + y;
        } else {
            out[(size_t)B_ROWS * STATE_DIM + rb] = y;
        }
    }
}

// ================= fallback fp32 path (used if ws too small) =================
#define FB_BM      16
#define FB_THREADS 256
#define FB_TILES   ((B_ROWS + FB_BM - 1) / FB_BM)

__launch_bounds__(FB_THREADS, 2)
__global__ void mlp_fp32_kernel(const float* __restrict__ state,
                                const float* __restrict__ action,
                                const float* __restrict__ eps,
                                const float* __restrict__ W1, const float* __restrict__ b1,
                                const float* __restrict__ W2, const float* __restrict__ b2,
                                const float* __restrict__ W3, const float* __restrict__ b3,
                                const int* __restrict__ cnt, const int* __restrict__ bucket,
                                float* __restrict__ out) {
    __shared__ float xs[FB_BM][IN_DIM];
    __shared__ float h1[FB_BM][HIDDEN];
    __shared__ float h2[FB_BM][HIDDEN];
    __shared__ float os[FB_BM][OUT_DIM];
    __shared__ int   rows[FB_BM];

    const int e    = blockIdx.x / FB_TILES;
    const int tile = blockIdx.x % FB_TILES;
    const int n    = cnt[e];
    const int m0   = tile * FB_BM;
    if (m0 >= n) return;
    const int nrows = min(FB_BM, n - m0);
    const int t = threadIdx.x;

    if (t < FB_BM) rows[t] = (t < nrows) ? bucket[e * B_ROWS + m0 + t] : bucket[e * B_ROWS + m0];
    __syncthreads();

    for (int i = t; i < FB_BM * IN_DIM; i += FB_THREADS) {
        int r = i / IN_DIM, c = i % IN_DIM;
        int rb = rows[r];
        xs[r][c] = (c < STATE_DIM) ? state[(size_t)rb * STATE_DIM + c]
                                   : action[(size_t)rb * ACTION_DIM + (c - STATE_DIM)];
    }
    __syncthreads();

    const int c0 = 2 * t;
    {
        const float* We = W1 + (size_t)e * IN_DIM * HIDDEN;
        float acc0[FB_BM], acc1[FB_BM];
        const float bias0 = b1[(size_t)e * HIDDEN + c0];
        const float bias1 = b1[(size_t)e * HIDDEN + c0 + 1];
        #pragma unroll
        for (int r = 0; r < FB_BM; ++r) { acc0[r] = bias0; acc1[r] = bias1; }
        for (int k = 0; k < IN_DIM; k += 4) {
            float2 w0 = *(const float2*)&We[(size_t)(k + 0) * HIDDEN + c0];
            float2 w1v = *(const float2*)&We[(size_t)(k + 1) * HIDDEN + c0];
            float2 w2v = *(const float2*)&We[(size_t)(k + 2) * HIDDEN + c0];
            float2 w3v = *(const float2*)&We[(size_t)(k + 3) * HIDDEN + c0];
            #pragma unroll
            for (int r = 0; r < FB_BM; ++r) {
                float4 x = *(const float4*)&xs[r][k];
                acc0[r] = fmaf(x.x, w0.x, acc0[r]); acc1[r] = fmaf(x.x, w0.y, acc1[r]);
                acc0[r] = fmaf(x.y, w1v.x, acc0[r]); acc1[r] = fmaf(x.y, w1v.y, acc1[r]);
                acc0[r] = fmaf(x.z, w2v.x, acc0[r]); acc1[r] = fmaf(x.z, w2v.y, acc1[r]);
                acc0[r] = fmaf(x.w, w3v.x, acc0[r]); acc1[r] = fmaf(x.w, w3v.y, acc1[r]);
            }
        }
        #pragma unroll
        for (int r = 0; r < FB_BM; ++r)
            *(float2*)&h1[r][c0] = make_float2(fmaxf(acc0[r], 0.f), fmaxf(acc1[r], 0.f));
    }
    __syncthreads();
    {
        const float* We = W2 + (size_t)e * HIDDEN * HIDDEN;
        float acc0[FB_BM], acc1[FB_BM];
        const float bias0 = b2[(size_t)e * HIDDEN + c0];
        const float bias1 = b2[(size_t)e * HIDDEN + c0 + 1];
        #pragma unroll
        for (int r = 0; r < FB_BM; ++r) { acc0[r] = bias0; acc1[r] = bias1; }
        for (int k = 0; k < HIDDEN; k += 4) {
            float2 w0 = *(const float2*)&We[(size_t)(k + 0) * HIDDEN + c0];
            float2 w1v = *(const float2*)&We[(size_t)(k + 1) * HIDDEN + c0];
            float2 w2v = *(const float2*)&We[(size_t)(k + 2) * HIDDEN + c0];
            float2 w3v = *(const float2*)&We[(size_t)(k + 3) * HIDDEN + c0];
            #pragma unroll
            for (int r = 0; r < FB_BM; ++r) {
                float4 x = *(const float4*)&h1[r][k];
                acc0[r] = fmaf(x.x, w0.x, acc0[r]); acc1[r] = fmaf(x.x, w0.y, acc1[r]);
                acc0[r] = fmaf(x.y, w1v.x, acc0[r]); acc1[r] = fmaf(x.y, w1v.y, acc1[r]);
                acc0[r] = fmaf(x.z, w2v.x, acc0[r]); acc1[r] = fmaf(x.z, w2v.y, acc1[r]);
                acc0[r] = fmaf(x.w, w3v.x, acc0[r]); acc1[r] = fmaf(x.w, w3v.y, acc1[r]);
            }
        }
        #pragma unroll
        for (int r = 0; r < FB_BM; ++r)
            *(float2*)&h2[r][c0] = make_float2(fmaxf(acc0[r], 0.f), fmaxf(acc1[r], 0.f));
    }
    __syncthreads();
    {
        const float* We = W3 + (size_t)e * HIDDEN * OUT_DIM;
        for (int i = t; i < FB_BM * OUT_DIM; i += FB_THREADS) {
            int r = i / OUT_DIM, c = i % OUT_DIM;
            float acc = b3[(size_t)e * OUT_DIM + c];
            for (int k = 0; k < HIDDEN; k += 4) {
                float4 h = *(const float4*)&h2[r][k];
                acc = fmaf(h.x, We[(size_t)(k + 0) * OUT_DIM + c], acc);
                acc = fmaf(h.y, We[(size_t)(k + 1) * OUT_DIM + c], acc);
                acc = fmaf(h.z, We[(size_t)(k + 2) * OUT_DIM + c], acc);
                acc = fmaf(h.w, We[(size_t)(k + 3) * OUT_DIM + c], acc);
            }
            os[r][c] = acc;
        }
    }
    __syncthreads();
    for (int i = t; i < FB_BM * D_OUT; i += FB_THREADS) {
        int r = i / D_OUT, c = i % D_OUT;
        if (r >= nrows) continue;
        int rb = rows[r];
        float mu = os[r][c];
        float ls = fminf(fmaxf(os[r][c + D_OUT], -20.f), 2.f);
        float y  = fmaf(expf(ls), eps[(size_t)rb * D_OUT + c], mu);
        if (c < STATE_DIM) out[(size_t)rb * STATE_DIM + c] = state[(size_t)rb * STATE_DIM + c] + y;
        else               out[(size_t)B_ROWS * STATE_DIM + rb] = y;
    }
}

extern "C" void kernel_launch(void* const* d_in, const int* in_sizes, int n_in,
                              void* d_out, int out_size, void* d_ws, size_t ws_size,
                              hipStream_t stream) {
    const float* state  = (const float*)d_in[0];
    const float* action = (const float*)d_in[1];
    const float* eps    = (const float*)d_in[2];
    const float* W1     = (const float*)d_in[3];
    const float* b1     = (const float*)d_in[4];
    const float* W2     = (const float*)d_in[5];
    const float* b2     = (const float*)d_in[6];
    const float* W3     = (const float*)d_in[7];
    const float* b3     = (const float*)d_in[8];
    const int*   idx    = (const int*)d_in[9];
    float* out = (float*)d_out;

    int* cnt    = (int*)((char*)d_ws + OFF_CNT);
    int* bucket = (int*)((char*)d_ws + OFF_BUCKET);

    hipMemsetAsync(cnt, 0, ENSEMBLE * sizeof(int), stream);

    if (ws_size >= WS_NEEDED) {
        _Float16* w1 = (_Float16*)((char*)d_ws + OFF_W1);
        _Float16* w2 = (_Float16*)((char*)d_ws + OFF_W2);
        _Float16* w3 = (_Float16*)((char*)d_ws + OFF_W3);

        prep_kernel<<<BUCKET_BLOCKS + PACK_BLOCKS, 256, 0, stream>>>(
            idx, cnt, bucket, W1, W2, W3, w1, w2, w3);

        mlp_mfma_kernel<<<NTILES, MTHREADS, 0, stream>>>(
            state, action, eps, b1, b2, b3, w1, w2, w3, cnt, bucket, out);
    } else {
        prep_kernel<<<BUCKET_BLOCKS, 256, 0, stream>>>(
            idx, cnt, bucket, W1, W2, W3, (_Float16*)0, (_Float16*)0, (_Float16*)0);
        mlp_fp32_kernel<<<TOP_K * FB_TILES, FB_THREADS, 0, stream>>>(
            state, action, eps, W1, b1, W2, b2, W3, b3, cnt, bucket, out);
    }
}

// Round 16
// 128.958 us; speedup vs baseline: 1.6285x; 1.1367x over previous
//
#include <hip/hip_runtime.h>
#include <math.h>

#define B_ROWS     32768
#define STATE_DIM  64
#define ACTION_DIM 16
#define HIDDEN     512
#define ENSEMBLE   7
#define TOP_K      5
#define IN_DIM     80    // STATE_DIM + ACTION_DIM
#define OUT_DIM    130   // 2*(STATE_DIM+1)
#define D_OUT      65    // STATE_DIM+1

// ---- MFMA kernel geometry ----
#define BM         32
#define MTHREADS   512                           // 8 waves, each 32 rows x 64 cols
#define NTILES     (B_ROWS / BM + TOP_K)         // 1029 — exact-grid upper bound

// ---- packed weight dims ----
#define L1_K8 12      // K=96 (real 80)
#define L2_K8 64      // K=512
#define L3_K8 64      // K=512
#define L3_N  144     // N=130 padded to 9 col-tiles

#define N_W1 (TOP_K * L1_K8 * HIDDEN * 8)
#define N_W2 (TOP_K * L2_K8 * HIDDEN * 8)
#define N_W3 (TOP_K * L3_K8 * L3_N * 8)

#define OFF_CNT    0
#define OFF_BUCKET 256
#define OFF_W1     (OFF_BUCKET + ENSEMBLE * B_ROWS * 4)
#define OFF_W2     (OFF_W1 + N_W1 * 2)
#define OFF_W3     (OFF_W2 + N_W2 * 2)
#define WS_NEEDED  ((size_t)(OFF_W3 + N_W3 * 2))

// prep kernel: first blocks bucket, rest pack
#define BUCKET_BLOCKS ((B_ROWS + 255) / 256)                     // 128
#define PACK_G        (TOP_K * (L1_K8*HIDDEN + L2_K8*HIDDEN + L3_K8*L3_N))
#define PACK_BLOCKS   ((PACK_G + 255) / 256)

typedef __attribute__((ext_vector_type(8))) _Float16 half8;
typedef __attribute__((ext_vector_type(4))) float f32x4;

// ---------------- prep: bucket rows + pack weights (fused, one launch) ----------------
__global__ void prep_kernel(const int* __restrict__ idx,
                            int* __restrict__ cnt,
                            int* __restrict__ bucket,
                            const float* __restrict__ W1, const float* __restrict__ W2,
                            const float* __restrict__ W3,
                            _Float16* __restrict__ w1, _Float16* __restrict__ w2,
                            _Float16* __restrict__ w3) {
    if (blockIdx.x < BUCKET_BLOCKS) {
        int b = blockIdx.x * 256 + threadIdx.x;
        int lane = threadIdx.x & 63;
        int e = -1;
        if (b < B_ROWS) e = min(max(idx[b], 0), TOP_K - 1);
        #pragma unroll
        for (int ev = 0; ev < TOP_K; ++ev) {
            unsigned long long m = __ballot(e == ev);
            if (m == 0ull) continue;
            int leader = __ffsll((unsigned long long)m) - 1;
            int base = 0;
            if (lane == leader) base = atomicAdd(&cnt[ev], __popcll(m));
            base = __shfl(base, leader);
            if (e == ev) {
                int rank = __popcll(m & ((1ull << lane) - 1ull));
                bucket[ev * B_ROWS + base + rank] = b;
            }
        }
        return;
    }
    const int G1 = L1_K8 * HIDDEN;
    const int G2 = L2_K8 * HIDDEN;
    const int G3 = L3_K8 * L3_N;
    const int GPE = G1 + G2 + G3;
    int g = (blockIdx.x - BUCKET_BLOCKS) * 256 + threadIdx.x;
    if (g >= TOP_K * GPE) return;
    int e = g / GPE, r = g % GPE;

    const float* src; _Float16* dd;
    size_t dst; int k8, n, Kreal, Nreal, srcN;
    if (r < G1) {
        k8 = r / HIDDEN; n = r % HIDDEN;
        src = W1 + (size_t)e * IN_DIM * HIDDEN; Kreal = IN_DIM; Nreal = HIDDEN; srcN = HIDDEN;
        dd = w1; dst = (((size_t)e * L1_K8 + k8) * HIDDEN + n) * 8;
    } else if (r < G1 + G2) {
        int rr = r - G1; k8 = rr / HIDDEN; n = rr % HIDDEN;
        src = W2 + (size_t)e * HIDDEN * HIDDEN; Kreal = HIDDEN; Nreal = HIDDEN; srcN = HIDDEN;
        dd = w2; dst = (((size_t)e * L2_K8 + k8) * HIDDEN + n) * 8;
    } else {
        int rr = r - G1 - G2; k8 = rr / L3_N; n = rr % L3_N;
        src = W3 + (size_t)e * HIDDEN * OUT_DIM; Kreal = HIDDEN; Nreal = OUT_DIM; srcN = OUT_DIM;
        dd = w3; dst = (((size_t)e * L3_K8 + k8) * L3_N + n) * 8;
    }
    half8 hv;
    #pragma unroll
    for (int j = 0; j < 8; ++j) {
        int k = k8 * 8 + j;
        float v = (k < Kreal && n < Nreal) ? src[(size_t)k * srcN + n] : 0.f;
        hv[j] = (_Float16)v;
    }
    *(half8*)(dd + dst) = hv;
}

// ---------------- GEMM compute: 32 rows x 64 cols per wave, 2-deep load window ----------------
// A in LDS (fp16, row stride ASTR bytes, optional XOR swizzle); B packed [k8][Bn][8] fp16.
// Pair-unrolled: 8 B-loads (2 k-steps) + 4 A-reads issued, then sched_barrier(0) pins
// them ahead of the 16 MFMAs — forces a 2x deeper load window than the compiler's default.
template<int ASTR, bool SWZ, int KSTEPS>
__device__ __forceinline__ void gemm_compute(
    const char* A,
    const _Float16* __restrict__ B, int Bn, const float* __restrict__ bias,
    f32x4 (&acc)[2][4], int lane, int col0)
{
    const int lc = lane & 15, kg = lane >> 4;
    #pragma unroll
    for (int ctl = 0; ctl < 4; ++ctl) {
        float b = bias[col0 + ctl * 16 + lc];
        acc[0][ctl] = (f32x4){b, b, b, b};
        acc[1][ctl] = acc[0][ctl];
    }
    const size_t bstep = (size_t)4 * Bn * 8;   // elements per k-step (K advances 32)
    const _Float16* bp = B + ((size_t)kg * Bn + col0 + lc) * 8;

    #pragma unroll
    for (int kp = 0; kp < KSTEPS / 2; ++kp) {
        const int ksA = 2 * kp, ksB = 2 * kp + 1;
        half8 bA[4], bB[4];
        #pragma unroll
        for (int ctl = 0; ctl < 4; ++ctl)
            bA[ctl] = *(const half8*)(bp + (size_t)ksA * bstep + ctl * 128);
        #pragma unroll
        for (int ctl = 0; ctl < 4; ++ctl)
            bB[ctl] = *(const half8*)(bp + (size_t)ksB * bstep + ctl * 128);
        half8 aA[2], aB[2];
        #pragma unroll
        for (int rt = 0; rt < 2; ++rt) {
            int row = rt * 16 + lc;
            int linA = row * ASTR + ksA * 64 + kg * 16;
            int linB = row * ASTR + ksB * 64 + kg * 16;
            if (SWZ) { linA ^= (row & 7) << 4; linB ^= (row & 7) << 4; }
            aA[rt] = *(const half8*)(A + linA);
            aB[rt] = *(const half8*)(A + linB);
        }
        __builtin_amdgcn_sched_barrier(0);   // loads stay above, MFMAs below
        #pragma unroll
        for (int rt = 0; rt < 2; ++rt)
        #pragma unroll
        for (int ctl = 0; ctl < 4; ++ctl)
            acc[rt][ctl] = __builtin_amdgcn_mfma_f32_16x16x32_f16(aA[rt], bA[ctl], acc[rt][ctl], 0, 0, 0);
        #pragma unroll
        for (int rt = 0; rt < 2; ++rt)
        #pragma unroll
        for (int ctl = 0; ctl < 4; ++ctl)
            acc[rt][ctl] = __builtin_amdgcn_mfma_f32_16x16x32_f16(aB[rt], bB[ctl], acc[rt][ctl], 0, 0, 0);
    }
    if (KSTEPS & 1) {
        const int ks = KSTEPS - 1;
        half8 bc[4];
        #pragma unroll
        for (int ctl = 0; ctl < 4; ++ctl)
            bc[ctl] = *(const half8*)(bp + (size_t)ks * bstep + ctl * 128);
        half8 ah[2];
        #pragma unroll
        for (int rt = 0; rt < 2; ++rt) {
            int row = rt * 16 + lc;
            int lin = row * ASTR + ks * 64 + kg * 16;
            if (SWZ) lin ^= (row & 7) << 4;
            ah[rt] = *(const half8*)(A + lin);
        }
        #pragma unroll
        for (int rt = 0; rt < 2; ++rt)
        #pragma unroll
        for (int ctl = 0; ctl < 4; ++ctl)
            acc[rt][ctl] = __builtin_amdgcn_mfma_f32_16x16x32_f16(ah[rt], bc[ctl], acc[rt][ctl], 0, 0, 0);
    }
}

// relu + fp16 + swizzled store into h region ([32][512] fp16, stride 1024B)
__device__ __forceinline__ void store_h(char* O, f32x4 (&acc)[2][4], int lane, int col0) {
    const int lc = lane & 15, kg = lane >> 4;
    #pragma unroll
    for (int rt = 0; rt < 2; ++rt)
    #pragma unroll
    for (int ctl = 0; ctl < 4; ++ctl)
    #pragma unroll
    for (int q = 0; q < 4; ++q) {
        int row = rt * 16 + kg * 4 + q;          // C layout: row=(lane>>4)*4+q
        int col = col0 + ctl * 16 + lc;          // C layout: col=lane&15
        float v = fmaxf(acc[rt][ctl][q], 0.f);
        int lin = (row * 1024 + col * 2) ^ ((row & 7) << 4);
        *(_Float16*)(O + lin) = (_Float16)v;
    }
}

// bijective XCD-chunk swizzle for NTILES workgroups on 8 XCDs (m204 variant)
__device__ __forceinline__ int xcd_swz(int orig) {
    const int nx = 8, q = NTILES / nx, r = NTILES % nx;
    int xcd = orig % nx, pos = orig / nx;
    int base = (xcd < r) ? xcd * (q + 1) : r * (q + 1) + (xcd - r) * q;
    return base + pos;
}

// ---------------- fused MLP, fp16 MFMA, BM=32, 8 waves (32x64 per wave) ----------------
__launch_bounds__(MTHREADS, 1)
__global__ void mlp_mfma_kernel(const float* __restrict__ state,
                                const float* __restrict__ action,
                                const float* __restrict__ eps,
                                const float* __restrict__ b1,
                                const float* __restrict__ b2,
                                const float* __restrict__ b3,
                                const _Float16* __restrict__ w1,
                                const _Float16* __restrict__ w2,
                                const _Float16* __restrict__ w3,
                                const int* __restrict__ cnt, const int* __restrict__ bucket,
                                float* __restrict__ out) {
    __shared__ char smem[39936];
    char* xs = smem;                     // [32][112] fp16, stride 224B (7168 B)
    char* hs = smem + 7168;              // [32][512] fp16 swizzled (32768 B) — h1 then h2
    float* os = (float*)(smem + 7168);   // [32][132] fp32 (16896 B), overlays h after layer 3

    // ---- exact-grid tile lookup: block j -> (e, tile), latched prefix scan ----
    const int j = xcd_swz(blockIdx.x);
    int e = TOP_K, base = 0;
    {
        int acct = 0;
        #pragma unroll
        for (int ev = 0; ev < TOP_K; ++ev) {
            int tiles = (cnt[ev] + BM - 1) / BM;
            if (e == TOP_K && j < acct + tiles) { e = ev; base = acct; }
            acct += tiles;
        }
    }
    if (e >= TOP_K) return;
    const int n    = cnt[e];
    const int tile = j - base;
    const int m0   = tile * BM;
    if (m0 >= n) return;
    const int nrows = min(BM, n - m0);
    const int t = threadIdx.x;
    const int lane = t & 63;
    const int wv = t >> 6;
    const int col0 = wv * 64;            // 8 col-groups x 64 cols
    const int* brow = bucket + (size_t)e * B_ROWS;

    // ---- stage x = concat(state, action) fp16, 32x112 (cols>=80 zero) ----
    for (int i = t; i < BM * 112; i += MTHREADS) {
        int r = i / 112, c = i % 112;
        int rb = brow[min(m0 + r, n - 1)];
        float v = 0.f;
        if (c < STATE_DIM)      v = state[(size_t)rb * STATE_DIM + c];
        else if (c < IN_DIM)    v = action[(size_t)rb * ACTION_DIM + (c - STATE_DIM)];
        *(_Float16*)(xs + r * 224 + c * 2) = (_Float16)v;
    }
    __syncthreads();

    f32x4 acc[2][4];

    // ---- layer 1: h1 = relu(x @ W1 + b1), K=96, N=512 ----
    gemm_compute<224, false, 3>(xs,
        w1 + (size_t)e * L1_K8 * HIDDEN * 8,
        HIDDEN, b1 + (size_t)e * HIDDEN, acc, lane, col0);
    store_h(hs, acc, lane, col0);        // h region disjoint from x: no WAR hazard
    __syncthreads();

    // ---- layer 2: h2 = relu(h1 @ W2 + b2), K=512, N=512; h2 in regs until barrier ----
    gemm_compute<1024, true, 16>(hs,
        w2 + (size_t)e * L2_K8 * HIDDEN * 8,
        HIDDEN, b2 + (size_t)e * HIDDEN, acc, lane, col0);
    __syncthreads();                     // all h1 reads complete
    store_h(hs, acc, lane, col0);        // overwrite h1 with h2
    __syncthreads();

    // ---- layer 3: o = h2 @ W3 + b3, K=512, N=144, pair-unrolled (2-deep window) ----
    // 18 units = 2 row-tiles x 9 col-tiles over 8 waves: rt=wv&1, ct0=wv>>1 (0..3),
    // cols {ct0, ct0+4}; waves 0,1 also ct=8.
    {
        const _Float16* Bw = w3 + (size_t)e * L3_K8 * L3_N * 8;
        const float* b3e = b3 + (size_t)e * OUT_DIM;
        const int lc = lane & 15, kg = lane >> 4;
        const int rt  = wv & 1;
        const int ct0 = wv >> 1;             // 0..3
        const bool third = (wv < 2);         // ct=8
        f32x4 o0 = {0.f,0.f,0.f,0.f}, o1 = o0, o2 = o0;
        const size_t bstep = (size_t)4 * L3_N * 8;
        const _Float16* bp0 = Bw + ((size_t)kg * L3_N + ct0 * 16 + lc) * 8;
        const _Float16* bp1 = Bw + ((size_t)kg * L3_N + (ct0 + 4) * 16 + lc) * 8;
        const _Float16* bp2 = Bw + ((size_t)kg * L3_N + 8 * 16 + lc) * 8;

        #pragma unroll
        for (int kp = 0; kp < 8; ++kp) {
            const int ksA = 2 * kp, ksB = 2 * kp + 1;
            half8 vA0 = *(const half8*)(bp0 + (size_t)ksA * bstep);
            half8 vA1 = *(const half8*)(bp1 + (size_t)ksA * bstep);
            half8 vB0 = *(const half8*)(bp0 + (size_t)ksB * bstep);
            half8 vB1 = *(const half8*)(bp1 + (size_t)ksB * bstep);
            half8 vA2, vB2;
            if (third) {
                vA2 = *(const half8*)(bp2 + (size_t)ksA * bstep);
                vB2 = *(const half8*)(bp2 + (size_t)ksB * bstep);
            }
            int row = rt * 16 + lc;
            int linA = (row * 1024 + ksA * 64 + kg * 16) ^ ((row & 7) << 4);
            int linB = (row * 1024 + ksB * 64 + kg * 16) ^ ((row & 7) << 4);
            half8 aA = *(const half8*)(hs + linA);
            half8 aB = *(const half8*)(hs + linB);
            __builtin_amdgcn_sched_barrier(0);
            o0 = __builtin_amdgcn_mfma_f32_16x16x32_f16(aA, vA0, o0, 0, 0, 0);
            o1 = __builtin_amdgcn_mfma_f32_16x16x32_f16(aA, vA1, o1, 0, 0, 0);
            if (third) o2 = __builtin_amdgcn_mfma_f32_16x16x32_f16(aA, vA2, o2, 0, 0, 0);
            o0 = __builtin_amdgcn_mfma_f32_16x16x32_f16(aB, vB0, o0, 0, 0, 0);
            o1 = __builtin_amdgcn_mfma_f32_16x16x32_f16(aB, vB1, o1, 0, 0, 0);
            if (third) o2 = __builtin_amdgcn_mfma_f32_16x16x32_f16(aB, vB2, o2, 0, 0, 0);
        }
        __syncthreads();                 // all h2 reads complete (os overlays h)
        {
            int c0 = ct0 * 16 + lc;
            int c1 = (ct0 + 4) * 16 + lc;
            #pragma unroll
            for (int q = 0; q < 4; ++q) {
                int row = rt * 16 + kg * 4 + q;
                os[row * 132 + c0] = o0[q] + b3e[c0];
                if (c1 < OUT_DIM) os[row * 132 + c1] = o1[q] + b3e[c1];
            }
            if (third) {
                int c2 = 128 + lc;
                if (c2 < OUT_DIM) {
                    #pragma unroll
                    for (int q = 0; q < 4; ++q) {
                        int row = rt * 16 + kg * 4 + q;
                        os[row * 132 + c2] = o2[q] + b3e[c2];
                    }
                }
            }
        }
    }
    __syncthreads();

    // ---- epilogue ----
    for (int i = t; i < BM * D_OUT; i += MTHREADS) {
        int r = i / D_OUT, c = i % D_OUT;
        if (r >= nrows) continue;
        int rb = brow[m0 + r];
        float mu = os[r * 132 + c];
        float ls = fminf(fmaxf(os[r * 132 + c + D_OUT], -20.f), 2.f);
        float y  = fmaf(expf(ls), eps[(size_t)rb * D_OUT + c], mu);
        if (c < STATE_DIM) {
            out[(size_t)rb * STATE_DIM + c] = state[(size_t)rb * STATE_DIM + c] + y;
        } else {
            out[(size_t)B_ROWS * STATE_DIM + rb] = y;
        }
    }
}

// ================= fallback fp32 path (used if ws too small) =================
#define FB_BM      16
#define FB_THREADS 256
#define FB_TILES   ((B_ROWS + FB_BM - 1) / FB_BM)

__launch_bounds__(FB_THREADS, 2)
__global__ void mlp_fp32_kernel(const float* __restrict__ state,
                                const float* __restrict__ action,
                                const float* __restrict__ eps,
                                const float* __restrict__ W1, const float* __restrict__ b1,
                                const float* __restrict__ W2, const float* __restrict__ b2,
                                const float* __restrict__ W3, const float* __restrict__ b3,
                                const int* __restrict__ cnt, const int* __restrict__ bucket,
                                float* __restrict__ out) {
    __shared__ float xs[FB_BM][IN_DIM];
    __shared__ float h1[FB_BM][HIDDEN];
    __shared__ float h2[FB_BM][HIDDEN];
    __shared__ float os[FB_BM][OUT_DIM];
    __shared__ int   rows[FB_BM];

    const int e    = blockIdx.x / FB_TILES;
    const int tile = blockIdx.x % FB_TILES;
    const int n    = cnt[e];
    const int m0   = tile * FB_BM;
    if (m0 >= n) return;
    const int nrows = min(FB_BM, n - m0);
    const int t = threadIdx.x;

    if (t < FB_BM) rows[t] = (t < nrows) ? bucket[e * B_ROWS + m0 + t] : bucket[e * B_ROWS + m0];
    __syncthreads();

    for (int i = t; i < FB_BM * IN_DIM; i += FB_THREADS) {
        int r = i / IN_DIM, c = i % IN_DIM;
        int rb = rows[r];
        xs[r][c] = (c < STATE_DIM) ? state[(size_t)rb * STATE_DIM + c]
                                   : action[(size_t)rb * ACTION_DIM + (c - STATE_DIM)];
    }
    __syncthreads();

    const int c0 = 2 * t;
    {
        const float* We = W1 + (size_t)e * IN_DIM * HIDDEN;
        float acc0[FB_BM], acc1[FB_BM];
        const float bias0 = b1[(size_t)e * HIDDEN + c0];
        const float bias1 = b1[(size_t)e * HIDDEN + c0 + 1];
        #pragma unroll
        for (int r = 0; r < FB_BM; ++r) { acc0[r] = bias0; acc1[r] = bias1; }
        for (int k = 0; k < IN_DIM; k += 4) {
            float2 w0 = *(const float2*)&We[(size_t)(k + 0) * HIDDEN + c0];
            float2 w1v = *(const float2*)&We[(size_t)(k + 1) * HIDDEN + c0];
            float2 w2v = *(const float2*)&We[(size_t)(k + 2) * HIDDEN + c0];
            float2 w3v = *(const float2*)&We[(size_t)(k + 3) * HIDDEN + c0];
            #pragma unroll
            for (int r = 0; r < FB_BM; ++r) {
                float4 x = *(const float4*)&xs[r][k];
                acc0[r] = fmaf(x.x, w0.x, acc0[r]); acc1[r] = fmaf(x.x, w0.y, acc1[r]);
                acc0[r] = fmaf(x.y, w1v.x, acc0[r]); acc1[r] = fmaf(x.y, w1v.y, acc1[r]);
                acc0[r] = fmaf(x.z, w2v.x, acc0[r]); acc1[r] = fmaf(x.z, w2v.y, acc1[r]);
                acc0[r] = fmaf(x.w, w3v.x, acc0[r]); acc1[r] = fmaf(x.w, w3v.y, acc1[r]);
            }
        }
        #pragma unroll
        for (int r = 0; r < FB_BM; ++r)
            *(float2*)&h1[r][c0] = make_float2(fmaxf(acc0[r], 0.f), fmaxf(acc1[r], 0.f));
    }
    __syncthreads();
    {
        const float* We = W2 + (size_t)e * HIDDEN * HIDDEN;
        float acc0[FB_BM], acc1[FB_BM];
        const float bias0 = b2[(size_t)e * HIDDEN + c0];
        const float bias1 = b2[(size_t)e * HIDDEN + c0 + 1];
        #pragma unroll
        for (int r = 0; r < FB_BM; ++r) { acc0[r] = bias0; acc1[r] = bias1; }
        for (int k = 0; k < HIDDEN; k += 4) {
            float2 w0 = *(const float2*)&We[(size_t)(k + 0) * HIDDEN + c0];
            float2 w1v = *(const float2*)&We[(size_t)(k + 1) * HIDDEN + c0];
            float2 w2v = *(const float2*)&We[(size_t)(k + 2) * HIDDEN + c0];
            float2 w3v = *(const float2*)&We[(size_t)(k + 3) * HIDDEN + c0];
            #pragma unroll
            for (int r = 0; r < FB_BM; ++r) {
                float4 x = *(const float4*)&h1[r][k];
                acc0[r] = fmaf(x.x, w0.x, acc0[r]); acc1[r] = fmaf(x.x, w0.y, acc1[r]);
                acc0[r] = fmaf(x.y, w1v.x, acc0[r]); acc1[r] = fmaf(x.y, w1v.y, acc1[r]);
                acc0[r] = fmaf(x.z, w2v.x, acc0[r]); acc1[r] = fmaf(x.z, w2v.y, acc1[r]);
                acc0[r] = fmaf(x.w, w3v.x, acc0[r]); acc1[r] = fmaf(x.w, w3v.y, acc1[r]);
            }
        }
        #pragma unroll
        for (int r = 0; r < FB_BM; ++r)
            *(float2*)&h2[r][c0] = make_float2(fmaxf(acc0[r], 0.f), fmaxf(acc1[r], 0.f));
    }
    __syncthreads();
    {
        const float* We = W3 + (size_t)e * HIDDEN * OUT_DIM;
        for (int i = t; i < FB_BM * OUT_DIM; i += FB_THREADS) {
            int r = i / OUT_DIM, c = i % OUT_DIM;
            float acc = b3[(size_t)e * OUT_DIM + c];
            for (int k = 0; k < HIDDEN; k += 4) {
                float4 h = *(const float4*)&h2[r][k];
                acc = fmaf(h.x, We[(size_t)(k + 0) * OUT_DIM + c], acc);
                acc = fmaf(h.y, We[(size_t)(k + 1) * OUT_DIM + c], acc);
                acc = fmaf(h.z, We[(size_t)(k + 2) * OUT_DIM + c], acc);
                acc = fmaf(h.w, We[(size_t)(k + 3) * OUT_DIM + c], acc);
            }
            os[r][c] = acc;
        }
    }
    __syncthreads();
    for (int i = t; i < FB_BM * D_OUT; i += FB_THREADS) {
        int r = i / D_OUT, c = i % D_OUT;
        if (r >= nrows) continue;
        int rb = rows[r];
        float mu = os[r][c];
        float ls = fminf(fmaxf(os[r][c + D_OUT], -20.f), 2.f);
        float y  = fmaf(expf(ls), eps[(size_t)rb * D_OUT + c], mu);
        if (c < STATE_DIM) out[(size_t)rb * STATE_DIM + c] = state[(size_t)rb * STATE_DIM + c] + y;
        else               out[(size_t)B_ROWS * STATE_DIM + rb] = y;
    }
}

extern "C" void kernel_launch(void* const* d_in, const int* in_sizes, int n_in,
                              void* d_out, int out_size, void* d_ws, size_t ws_size,
                              hipStream_t stream) {
    const float* state  = (const float*)d_in[0];
    const float* action = (const float*)d_in[1];
    const float* eps    = (const float*)d_in[2];
    const float* W1     = (const float*)d_in[3];
    const float* b1     = (const float*)d_in[4];
    const float* W2     = (const float*)d_in[5];
    const float* b2     = (const float*)d_in[6];
    const float* W3     = (const float*)d_in[7];
    const float* b3     = (const float*)d_in[8];
    const int*   idx    = (const int*)d_in[9];
    float* out = (float*)d_out;

    int* cnt    = (int*)((char*)d_ws + OFF_CNT);
    int* bucket = (int*)((char*)d_ws + OFF_BUCKET);

    hipMemsetAsync(cnt, 0, ENSEMBLE * sizeof(int), stream);

    if (ws_size >= WS_NEEDED) {
        _Float16* w1 = (_Float16*)((char*)d_ws + OFF_W1);
        _Float16* w2 = (_Float16*)((char*)d_ws + OFF_W2);
        _Float16* w3 = (_Float16*)((char*)d_ws + OFF_W3);

        prep_kernel<<<BUCKET_BLOCKS + PACK_BLOCKS, 256, 0, stream>>>(
            idx, cnt, bucket, W1, W2, W3, w1, w2, w3);

        mlp_mfma_kernel<<<NTILES, MTHREADS, 0, stream>>>(
            state, action, eps, b1, b2, b3, w1, w2, w3, cnt, bucket, out);
    } else {
        prep_kernel<<<BUCKET_BLOCKS, 256, 0, stream>>>(
            idx, cnt, bucket, W1, W2, W3, (_Float16*)0, (_Float16*)0, (_Float16*)0);
        mlp_fp32_kernel<<<TOP_K * FB_TILES, FB_THREADS, 0, stream>>>(
            state, action, eps, W1, b1, W2, b2, W3, b3, cnt, bucket, out);
    }
}